// Round 15
// baseline (297.071 us; speedup 1.0000x reference)
//
#include <hip/hip_runtime.h>

typedef __attribute__((ext_vector_type(8))) short short8;
typedef __attribute__((ext_vector_type(4))) float floatx4;

#define B_  64
#define N_  4096
#define DIN 192
#define S_  11
#define E_  128

__device__ inline unsigned short f2bf(float f) {
    union { float f; unsigned u; } v; v.f = f;
    unsigned r = v.u + 0x7FFF + ((v.u >> 16) & 1);
    return (unsigned short)(r >> 16);
}
__device__ inline floatx4 fzero4() { floatx4 v; v[0]=v[1]=v[2]=v[3]=0.f; return v; }
__device__ inline void store_bf4(unsigned short* dst, floatx4 v) {
    union { unsigned short u[4]; unsigned long long q; } o;
    o.u[0] = f2bf(v[0]); o.u[1] = f2bf(v[1]); o.u[2] = f2bf(v[2]); o.u[3] = f2bf(v[3]);
    *(unsigned long long*)dst = o.q;
}
__device__ inline float dot128(const float* __restrict__ w, const float* __restrict__ x) {
    const floatx4* wv = (const floatx4*)w;
    const floatx4* xv = (const floatx4*)x;
    float a = 0.f;
    for (int j = 0; j < 32; ++j) {
        floatx4 w_ = wv[j], x_ = xv[j];
        a += w_[0]*x_[0] + w_[1]*x_[1] + w_[2]*x_[2] + w_[3]*x_[3];
    }
    return a;
}
__device__ inline float dot256(const float* __restrict__ w, const float* __restrict__ x) {
    const floatx4* wv = (const floatx4*)w;
    const floatx4* xv = (const floatx4*)x;
    float a = 0.f;
    for (int j = 0; j < 64; ++j) {
        floatx4 w_ = wv[j], x_ = xv[j];
        a += w_[0]*x_[0] + w_[1]*x_[1] + w_[2]*x_[2] + w_[3]*x_[3];
    }
    return a;
}

// ---------------------------------------------------------------- K0: weight prep
__global__ void k0_prep(const float* __restrict__ Wk, const float* __restrict__ Wv,
                        const float* __restrict__ ln_in_g, const float* __restrict__ ln_in_b,
                        const float* __restrict__ Wq, const float* __restrict__ ln_s_g,
                        const float* __restrict__ ln_s_b,
                        unsigned short* __restrict__ Wf, float* __restrict__ bias_kv,
                        float* __restrict__ Wq_s, float* __restrict__ bias_q) {
    int o = blockIdx.x, t = threadIdx.x;
    if (o < 256) {
        const float* src = (o < 128) ? (Wk + (size_t)o * DIN) : (Wv + (size_t)(o - 128) * DIN);
        int nt = o >> 4, cc = o & 15;
        float bs = 0.f;
        for (int j = t; j < DIN; j += 64) {
            float w = src[j];
            int kk = j >> 5, gg = (j >> 3) & 3, jj = j & 7;
            Wf[(size_t)(((nt * 6 + kk) << 6) + gg * 16 + cc) * 8 + jj] = f2bf(w * ln_in_g[j]);
            bs += w * ln_in_b[j];
        }
        #pragma unroll
        for (int off = 32; off > 0; off >>= 1) bs += __shfl_down(bs, off);
        if (t == 0) bias_kv[o] = bs;
    } else {
        int e = o - 256;
        const float sc = 0.08838834764831845f;  // 1/sqrt(128)
        float bs = 0.f;
        for (int j = t; j < E_; j += 64) {
            float w = Wq[(size_t)e * E_ + j];
            Wq_s[(size_t)e * E_ + j] = w * ln_s_g[j] * sc;
            bs += w * ln_s_b[j];
        }
        #pragma unroll
        for (int off = 32; off > 0; off >>= 1) bs += __shfl_down(bs, off);
        if (t == 0) bias_q[e] = bs * sc;
    }
}

// ---------------------------------------------------------------- K0t: transposed weights for k5
__global__ __launch_bounds__(128)
void k0t_prep(const float* __restrict__ wih, const float* __restrict__ whh,
              const float* __restrict__ w1, const float* __restrict__ w2,
              const float* __restrict__ Wq, const float* __restrict__ ln_s_g,
              float* __restrict__ Wg, float* __restrict__ W1t,
              float* __restrict__ W2t, float* __restrict__ Wqt) {
    int blk = blockIdx.x, t = threadIdx.x;
    if (blk < 128) {
        int j = blk;
        for (int o = t; o < 768; o += 128)
            Wg[(size_t)j * 768 + o] = (o < 384) ? wih[(size_t)o * 128 + j]
                                               : whh[(size_t)(o - 384) * 128 + j];
    } else if (blk < 256) {
        int j = blk - 128;
        for (int k = t; k < 256; k += 128)
            W1t[(size_t)j * 256 + k] = w1[(size_t)k * 128 + j];
    } else if (blk < 512) {
        int j = blk - 256;
        W2t[(size_t)j * 128 + t] = w2[(size_t)t * 256 + j];
    } else {
        int j = blk - 512;
        const float sc = 0.08838834764831845f;
        Wqt[(size_t)j * 128 + t] = Wq[(size_t)t * 128 + j] * ln_s_g[j] * sc;
    }
}

// ---------------------------------------------------------------- K1: LN + K/V projection (M=64, high occupancy)
__global__ __launch_bounds__(512, 2)
void k1_lnproj(const float* __restrict__ inp, const unsigned short* __restrict__ Wf,
               const float* __restrict__ bias_kv,
               unsigned short* __restrict__ k1o, unsigned short* __restrict__ v1T) {
    __shared__ short8 Al[4 * 6 * 64];   // 24 KB: [rg][kk][lane]
    int t = threadIdx.x, lane = t & 63, wid = t >> 6;
    long rowbase = (long)blockIdx.x * 64;
    int bb = (int)(rowbase >> 12);
    int nbase = (int)(rowbase & 4095);
    int c = lane & 15, g = lane >> 4;
    int nt0 = wid * 2;

    short8 wf[2][6];
    #pragma unroll
    for (int p = 0; p < 2; ++p)
        #pragma unroll
        for (int kk = 0; kk < 6; ++kk)
            wf[p][kk] = *(const short8*)(Wf + (size_t)(((nt0 + p) * 6 + kk) * 64 + lane) * 8);

    if (wid < 4) {
        // waves 0-3 stage rows rowbase + wid*16 + c (64 rows total)
        long row = rowbase + wid * 16 + c;
        const float* rp = inp + row * DIN;
        floatx4 x[12];
        #pragma unroll
        for (int kk = 0; kk < 6; ++kk) {
            x[2 * kk]     = *(const floatx4*)(rp + kk * 32 + g * 8);
            x[2 * kk + 1] = *(const floatx4*)(rp + kk * 32 + g * 8 + 4);
        }
        float s1 = 0.f, s2 = 0.f;
        #pragma unroll
        for (int j = 0; j < 12; ++j)
            #pragma unroll
            for (int e = 0; e < 4; ++e) { s1 += x[j][e]; s2 += x[j][e] * x[j][e]; }
        s1 += __shfl_xor(s1, 16); s1 += __shfl_xor(s1, 32);
        s2 += __shfl_xor(s2, 16); s2 += __shfl_xor(s2, 32);
        float mean = s1 * (1.f / 192.f);
        float var  = s2 * (1.f / 192.f) - mean * mean;
        float rsd  = rsqrtf(var + 1e-5f);
        #pragma unroll
        for (int kk = 0; kk < 6; ++kk) {
            short8 f;
            #pragma unroll
            for (int e = 0; e < 4; ++e) {
                f[e]     = (short)f2bf((x[2 * kk][e]     - mean) * rsd);
                f[4 + e] = (short)f2bf((x[2 * kk + 1][e] - mean) * rsd);
            }
            Al[(wid * 6 + kk) * 64 + lane] = f;
        }
    }
    __syncthreads();

    floatx4 acc[2][4];
    #pragma unroll
    for (int p = 0; p < 2; ++p)
        #pragma unroll
        for (int rg = 0; rg < 4; ++rg) acc[p][rg] = fzero4();

    if (wid < 4) {
        // K tiles (swapped operands)
        #pragma unroll
        for (int rg = 0; rg < 4; ++rg)
            #pragma unroll
            for (int kk = 0; kk < 6; ++kk) {
                short8 a = Al[(rg * 6 + kk) * 64 + lane];
                acc[0][rg] = __builtin_amdgcn_mfma_f32_16x16x32_bf16(wf[0][kk], a, acc[0][rg], 0, 0, 0);
                acc[1][rg] = __builtin_amdgcn_mfma_f32_16x16x32_bf16(wf[1][kk], a, acc[1][rg], 0, 0, 0);
            }
        #pragma unroll
        for (int p = 0; p < 2; ++p) {
            int nt = nt0 + p;
            floatx4 bia = *(const floatx4*)(bias_kv + nt * 16 + g * 4);
            #pragma unroll
            for (int rg = 0; rg < 4; ++rg) {
                floatx4 vv;
                #pragma unroll
                for (int r = 0; r < 4; ++r) vv[r] = acc[p][rg][r] + bia[r];
                store_bf4(k1o + (size_t)(rowbase + rg * 16 + c) * 128 + nt * 16 + g * 4, vv);
            }
        }
    } else {
        // V tiles (normal operands)
        #pragma unroll
        for (int rg = 0; rg < 4; ++rg)
            #pragma unroll
            for (int kk = 0; kk < 6; ++kk) {
                short8 a = Al[(rg * 6 + kk) * 64 + lane];
                acc[0][rg] = __builtin_amdgcn_mfma_f32_16x16x32_bf16(a, wf[0][kk], acc[0][rg], 0, 0, 0);
                acc[1][rg] = __builtin_amdgcn_mfma_f32_16x16x32_bf16(a, wf[1][kk], acc[1][rg], 0, 0, 0);
            }
        #pragma unroll
        for (int p = 0; p < 2; ++p) {
            int d = (nt0 + p - 8) * 16 + c;
            float bia = bias_kv[128 + d];
            size_t base = (((size_t)bb * 128 + d) << 12) + nbase;
            #pragma unroll
            for (int rg = 0; rg < 4; ++rg) {
                floatx4 vv;
                #pragma unroll
                for (int r = 0; r < 4; ++r) vv[r] = acc[p][rg][r] + bia;
                store_bf4(v1T + base + rg * 16 + g * 4, vv);
            }
        }
    }
}

// ---------------------------------------------------------------- K2a: LN(islots) + qkv projection (per b,s)
__global__ __launch_bounds__(128)
void k2a_slots(const float* __restrict__ islots, const int* __restrict__ ip,
               const float* __restrict__ ln_s_g, const float* __restrict__ ln_s_b,
               const float* __restrict__ in_w, const float* __restrict__ in_b,
               const float* __restrict__ Wq_s, const float* __restrict__ bias_q,
               float* __restrict__ slbuf, float* __restrict__ qkvbuf,
               float* __restrict__ slotsA, float* __restrict__ qbuf) {
    __shared__ float sl[128];
    __shared__ float sn[128];
    __shared__ float red[4];
    int t = threadIdx.x;
    size_t bs = blockIdx.x;
    float x = islots[bs * 128 + t];
    float s1 = x, s2 = x * x;
    #pragma unroll
    for (int off = 32; off > 0; off >>= 1) { s1 += __shfl_xor(s1, off); s2 += __shfl_xor(s2, off); }
    if ((t & 63) == 0) { red[(t >> 6) * 2] = s1; red[(t >> 6) * 2 + 1] = s2; }
    __syncthreads();
    float tot1 = red[0] + red[2], tot2 = red[1] + red[3];
    float mean = tot1 * (1.f / 128.f), var = tot2 * (1.f / 128.f) - mean * mean;
    float rs = rsqrtf(var + 1e-5f);
    float slv = (x - mean) * rs * ln_s_g[t] + ln_s_b[t];
    sl[t] = slv;
    slbuf[bs * 128 + t] = slv;
    __syncthreads();
    int ival = *ip;
    if (ival != 1) {
        #pragma unroll
        for (int kI = 0; kI < 3; ++kI) {
            int e = t + kI * 128;
            qkvbuf[bs * 384 + e] = dot128(in_w + (size_t)e * 128, sl) + in_b[e];
        }
    } else {
        slotsA[bs * 128 + t] = slv;
        float q1 = slv, q2 = slv * slv;
        #pragma unroll
        for (int off = 32; off > 0; off >>= 1) { q1 += __shfl_xor(q1, off); q2 += __shfl_xor(q2, off); }
        __syncthreads();
        if ((t & 63) == 0) { red[(t >> 6) * 2] = q1; red[(t >> 6) * 2 + 1] = q2; }
        __syncthreads();
        float qt1 = red[0] + red[2], qt2 = red[1] + red[3];
        float qmean = qt1 * (1.f / 128.f), qvar = qt2 * (1.f / 128.f) - qmean * qmean;
        float qrs = rsqrtf(qvar + 1e-5f);
        sn[t] = (slv - qmean) * qrs;
        __syncthreads();
        qbuf[bs * 128 + t] = dot128(Wq_s + (size_t)t * 128, sn) + bias_q[t];
    }
}

// ---------------------------------------------------------------- K2b: MHA + MLP + q (per b,s)
__global__ __launch_bounds__(128)
void k2b_mha(const int* __restrict__ ip, const float* __restrict__ qkvbuf,
             const float* __restrict__ slbuf,
             const float* __restrict__ out_w, const float* __restrict__ out_b,
             const float* __restrict__ w1, const float* __restrict__ b1,
             const float* __restrict__ w2, const float* __restrict__ b2,
             const float* __restrict__ ln_s_g, const float* __restrict__ ln_s_b,
             const float* __restrict__ Wq_s, const float* __restrict__ bias_q,
             float* __restrict__ slotsA, float* __restrict__ qbuf) {
    if (*ip == 1) return;
    __shared__ float qv[128];
    __shared__ float att[4][12];
    __shared__ float oh[128];
    __shared__ float s3[128];
    __shared__ float h1[256];
    __shared__ float sn[128];
    __shared__ float red[4];
    int t = threadIdx.x;
    int bb = blockIdx.x / 11, s = blockIdx.x % 11;
    size_t base = (size_t)bb * 11;
    qv[t] = qkvbuf[(base + s) * 384 + t];
    __syncthreads();
    if (t < 44) {
        int h = t / 11, j = t % 11;
        const float* kr = qkvbuf + (base + j) * 384 + 128 + h * 32;
        const float* qr = &qv[h * 32];
        float a = 0.f;
        #pragma unroll
        for (int d = 0; d < 32; ++d) a += qr[d] * kr[d];
        att[h][j] = a * 0.17677669529663687f;
    }
    __syncthreads();
    if (t < 4) {
        float mx = -1e30f;
        #pragma unroll
        for (int j = 0; j < 11; ++j) mx = fmaxf(mx, att[t][j]);
        float sum = 0.f, e_[11];
        #pragma unroll
        for (int j = 0; j < 11; ++j) { e_[j] = __expf(att[t][j] - mx); sum += e_[j]; }
        float inv = 1.f / sum;
        #pragma unroll
        for (int j = 0; j < 11; ++j) att[t][j] = e_[j] * inv;
    }
    __syncthreads();
    {
        int h = t >> 5;
        float a = 0.f;
        #pragma unroll
        for (int j = 0; j < 11; ++j) a += att[h][j] * qkvbuf[(base + j) * 384 + 256 + t];
        oh[t] = a;
    }
    __syncthreads();
    float slv = slbuf[(base + s) * 128 + t];
    float s2v = slv + dot128(out_w + (size_t)t * 128, oh) + out_b[t];
    float s1 = s2v, s2 = s2v * s2v;
    #pragma unroll
    for (int off = 32; off > 0; off >>= 1) { s1 += __shfl_xor(s1, off); s2 += __shfl_xor(s2, off); }
    if ((t & 63) == 0) { red[(t >> 6) * 2] = s1; red[(t >> 6) * 2 + 1] = s2; }
    __syncthreads();
    float tot1 = red[0] + red[2], tot2 = red[1] + red[3];
    float mean = tot1 * (1.f / 128.f), var = tot2 * (1.f / 128.f) - mean * mean;
    float rs = rsqrtf(var + 1e-5f);
    float s3v = (s2v - mean) * rs * ln_s_g[t] + ln_s_b[t];
    s3[t] = s3v;
    __syncthreads();
    #pragma unroll
    for (int kI = 0; kI < 2; ++kI) {
        int k = t + kI * 128;
        float a = dot128(w1 + (size_t)k * 128, s3) + b1[k];
        h1[k] = a > 0.f ? a : 0.f;
    }
    __syncthreads();
    float fin = s3v + dot256(w2 + (size_t)t * 256, h1) + b2[t];
    slotsA[(base + s) * 128 + t] = fin;
    float q1 = fin, q2 = fin * fin;
    #pragma unroll
    for (int off = 32; off > 0; off >>= 1) { q1 += __shfl_xor(q1, off); q2 += __shfl_xor(q2, off); }
    __syncthreads();
    if ((t & 63) == 0) { red[(t >> 6) * 2] = q1; red[(t >> 6) * 2 + 1] = q2; }
    __syncthreads();
    float qt1 = red[0] + red[2], qt2 = red[1] + red[3];
    float qmean = qt1 * (1.f / 128.f), qvar = qt2 * (1.f / 128.f) - qmean * qmean;
    float qrs = rsqrtf(qvar + 1e-5f);
    sn[t] = (fin - qmean) * qrs;
    __syncthreads();
    qbuf[(base + s) * 128 + t] = dot128(Wq_s + (size_t)t * 128, sn) + bias_q[t];
}

// ---------------------------------------------------------------- K4: slot attention main (barrier-free, per-wave partials)
#define LGP 13
#define PPAD 72
struct K4Arena {
    float Lg[64][LGP];            // 3328 B
    unsigned short Pl[16][PPAD];  // 2304 B
};
__global__ __launch_bounds__(256)
void k4_attn(const unsigned short* __restrict__ k1, const unsigned short* __restrict__ v1T,
             const float* __restrict__ qbuf, float* __restrict__ Upart, float* __restrict__ Spart) {
    __shared__ K4Arena ar[4];   // 22528 B
    int t = threadIdx.x, lane = t & 63, wid = t >> 6;
    int bb = blockIdx.x >> 4;
    int part = blockIdx.x & 15;
    int n0 = part * 256 + wid * 64;
    int pidx = part * 4 + wid;   // 64 partials per batch
    int c = lane & 15, g = lane >> 4;
    K4Arena& A = ar[wid];

    short8 bq[4];
    #pragma unroll
    for (int kk = 0; kk < 4; ++kk) {
        short8 f;
        if (c < 11) {
            const floatx4* qp = (const floatx4*)(qbuf + ((size_t)bb * 11 + c) * 128 + kk * 32 + g * 8);
            floatx4 q0 = qp[0], q1 = qp[1];
            #pragma unroll
            for (int e = 0; e < 4; ++e) { f[e] = (short)f2bf(q0[e]); f[4 + e] = (short)f2bf(q1[e]); }
        } else {
            #pragma unroll
            for (int e = 0; e < 8; ++e) f[e] = 0;
        }
        bq[kk] = f;
    }

    floatx4 lac[4];
    #pragma unroll
    for (int t4 = 0; t4 < 4; ++t4) {
        lac[t4] = fzero4();
        #pragma unroll
        for (int kk = 0; kk < 4; ++kk) {
            const short8* ap = (const short8*)(k1 + ((size_t)bb * 4096 + n0 + t4 * 16 + c) * 128 + kk * 32 + g * 8);
            lac[t4] = __builtin_amdgcn_mfma_f32_16x16x32_bf16(*ap, bq[kk], lac[t4], 0, 0, 0);
        }
    }
    if (c < LGP) {
        #pragma unroll
        for (int t4 = 0; t4 < 4; ++t4)
            #pragma unroll
            for (int r = 0; r < 4; ++r)
                A.Lg[t4 * 16 + g * 4 + r][c] = lac[t4][r];
    }

    float p[11];
    {
        float mx = -1e30f;
        #pragma unroll
        for (int s = 0; s < 11; ++s) { p[s] = A.Lg[lane][s]; mx = fmaxf(mx, p[s]); }
        float sum = 0.f;
        #pragma unroll
        for (int s = 0; s < 11; ++s) { p[s] = __expf(p[s] - mx); sum += p[s]; }
        float inv = 1.f / sum;
        #pragma unroll
        for (int s = 0; s < 11; ++s) p[s] = p[s] * inv + 1e-8f;
    }
    #pragma unroll
    for (int s = 0; s < 11; ++s) A.Pl[s][lane] = f2bf(p[s]);

    floatx4 uac[8];
    floatx4 sac = fzero4();
    #pragma unroll
    for (int dt = 0; dt < 8; ++dt) uac[dt] = fzero4();
    short8 ones;
    #pragma unroll
    for (int e = 0; e < 8; ++e) ones[e] = (short)0x3F80;
    #pragma unroll
    for (int kk = 0; kk < 2; ++kk) {
        short8 ap = *(const short8*)(&A.Pl[c][kk * 32 + g * 8]);
        #pragma unroll
        for (int dt = 0; dt < 8; ++dt) {
            const short8* vp = (const short8*)(v1T + ((size_t)bb * 128 + dt * 16 + c) * 4096 + n0 + kk * 32 + g * 8);
            uac[dt] = __builtin_amdgcn_mfma_f32_16x16x32_bf16(ap, *vp, uac[dt], 0, 0, 0);
        }
        sac = __builtin_amdgcn_mfma_f32_16x16x32_bf16(ap, ones, sac, 0, 0, 0);
    }
    size_t ub = ((size_t)bb * 64 + pidx) * 11;
    #pragma unroll
    for (int r = 0; r < 4; ++r) {
        int s = g * 4 + r;
        if (s < 11) {
            #pragma unroll
            for (int dt = 0; dt < 8; ++dt)
                Upart[(ub + s) * 128 + dt * 16 + c] = uac[dt][r];
            if (c == 0) Spart[ub + s] = sac[r];
        }
    }
}

// ---------------------------------------------------------------- KR: reduce 64 partials -> updbuf (streaming)
__global__ __launch_bounds__(256)
void kr_reduce(const float* __restrict__ Upart, const float* __restrict__ Spart,
               float* __restrict__ updbuf) {
    __shared__ float updp[8][128];
    __shared__ float redS;
    int t = threadIdx.x;
    int bb = blockIdx.x / 11, s = blockIdx.x % 11;
    {
        int p = t >> 5, c4 = t & 31;
        size_t base = ((size_t)bb * 704 + s) * 128;
        floatx4 acc = fzero4();
        #pragma unroll
        for (int i = 0; i < 8; ++i) {
            const floatx4* rp = (const floatx4*)(Upart + base + (size_t)(p * 8 + i) * 1408);
            acc += rp[c4];
        }
        *(floatx4*)&updp[p][c4 * 4] = acc;
    }
    if (t < 64) {
        float sa = Spart[(size_t)bb * 704 + (size_t)t * 11 + s];
        #pragma unroll
        for (int off = 32; off > 0; off >>= 1) sa += __shfl_xor(sa, off);
        if (t == 0) redS = sa;
    }
    __syncthreads();
    if (t < 128) {
        float ua = 0.f;
        #pragma unroll
        for (int p = 0; p < 8; ++p) ua += updp[p][t];
        updbuf[((size_t)bb * 11 + s) * 128 + t] = ua / redS;
    }
}

// ---------------------------------------------------------------- K5: coalesced-transposed GRU + LN + MLP (+ q)
__global__ __launch_bounds__(256)
void k5_gru(const float* __restrict__ updbuf,
            const float* __restrict__ slots_prev,
            const float* __restrict__ Wg,
            const float* __restrict__ bih, const float* __restrict__ bhh,
            const float* __restrict__ ln_m_g, const float* __restrict__ ln_m_b,
            const float* __restrict__ W1t, const float* __restrict__ b1,
            const float* __restrict__ W2t, const float* __restrict__ b2,
            const float* __restrict__ Wqt, const float* __restrict__ bias_q,
            float* __restrict__ out, float* __restrict__ qbuf, int compute_q) {
    __shared__ float upd[128];
    __shared__ float sp[128];
    __shared__ float gL[768];
    __shared__ float nsb[128];
    __shared__ float mrow[128];
    __shared__ float hrow[256];
    __shared__ float part2[2][128];
    __shared__ float red[4];
    __shared__ float snq[128];
    int t = threadIdx.x;
    int bb = blockIdx.x / 11, s = blockIdx.x % 11;
    size_t rowoff = ((size_t)bb * 11 + s) * 128;
    if (t < 128) {
        upd[t] = updbuf[rowoff + t];
        sp[t]  = slots_prev[rowoff + t];
    }
    __syncthreads();
    {
        const float* x1 = (t < 128) ? upd : sp;
        float a0 = 0.f, a1 = 0.f, a2 = 0.f;
        for (int j = 0; j < 128; ++j) {
            const float* wr = Wg + (size_t)j * 768;
            float xu = upd[j], xs = sp[j];
            a0 = fmaf(wr[t],       xu,    a0);
            a1 = fmaf(wr[t + 256], x1[j], a1);
            a2 = fmaf(wr[t + 512], xs,    a2);
        }
        float b0 = bih[t];
        float b1g = (t < 128) ? bih[t + 256] : bhh[t - 128];
        float b2g = bhh[t + 128];
        gL[t]       = a0 + b0;
        gL[t + 256] = a1 + b1g;
        gL[t + 512] = a2 + b2g;
    }
    __syncthreads();
    if (t < 128) {
        float r = 1.f / (1.f + __expf(-(gL[t] + gL[384 + t])));
        float z = 1.f / (1.f + __expf(-(gL[128 + t] + gL[512 + t])));
        float nn = tanhf(gL[256 + t] + r * gL[640 + t]);
        float ns = (1.f - z) * nn + z * sp[t];
        nsb[t] = ns;
        float s1 = ns, s2 = ns * ns;
        #pragma unroll
        for (int off = 32; off > 0; off >>= 1) { s1 += __shfl_xor(s1, off); s2 += __shfl_xor(s2, off); }
        if ((t & 63) == 0) { red[(t >> 6) * 2] = s1; red[(t >> 6) * 2 + 1] = s2; }
    }
    __syncthreads();
    if (t < 128) {
        float tot1 = red[0] + red[2], tot2 = red[1] + red[3];
        float mean = tot1 * (1.f / 128.f), var = tot2 * (1.f / 128.f) - mean * mean;
        float rs = rsqrtf(var + 1e-5f);
        mrow[t] = (nsb[t] - mean) * rs * ln_m_g[t] + ln_m_b[t];
    }
    __syncthreads();
    {
        float a = 0.f;
        for (int j = 0; j < 128; ++j) a = fmaf(W1t[(size_t)j * 256 + t], mrow[j], a);
        a += b1[t];
        hrow[t] = a > 0.f ? a : 0.f;
    }
    __syncthreads();
    {
        int half = t >> 7, e = t & 127;
        float a = 0.f;
        for (int j = 0; j < 128; ++j)
            a = fmaf(W2t[(size_t)(half * 128 + j) * 128 + e], hrow[half * 128 + j], a);
        part2[half][e] = a;
    }
    __syncthreads();
    float val = 0.f;
    if (t < 128) {
        val = nsb[t] + part2[0][t] + part2[1][t] + b2[t];
        out[rowoff + t] = val;
    }
    if (!compute_q) return;
    __syncthreads();
    if (t < 128) {
        float q1 = val, q2 = val * val;
        #pragma unroll
        for (int off = 32; off > 0; off >>= 1) { q1 += __shfl_xor(q1, off); q2 += __shfl_xor(q2, off); }
        if ((t & 63) == 0) { red[(t >> 6) * 2] = q1; red[(t >> 6) * 2 + 1] = q2; }
    }
    __syncthreads();
    if (t < 128) {
        float qt1 = red[0] + red[2], qt2 = red[1] + red[3];
        float qmean = qt1 * (1.f / 128.f), qvar = qt2 * (1.f / 128.f) - qmean * qmean;
        float qrs = rsqrtf(qvar + 1e-5f);
        snq[t] = (val - qmean) * qrs;
    }
    __syncthreads();
    {
        int half = t >> 7, e = t & 127;
        float a = 0.f;
        for (int j = 0; j < 64; ++j)
            a = fmaf(Wqt[(size_t)(half * 64 + j) * 128 + e], snq[half * 64 + j], a);
        part2[half][e] = a;
    }
    __syncthreads();
    if (t < 128)
        qbuf[rowoff + t] = part2[0][t] + part2[1][t] + bias_q[t];
}

// ---------------------------------------------------------------- host
extern "C" void kernel_launch(void* const* d_in, const int* in_sizes, int n_in,
                              void* d_out, int out_size, void* d_ws, size_t ws_size,
                              hipStream_t stream) {
    const float* inputs   = (const float*)d_in[0];
    const float* islots   = (const float*)d_in[1];
    const int*   ip       = (const int*)d_in[2];
    const float* ln_in_g  = (const float*)d_in[3];
    const float* ln_in_b  = (const float*)d_in[4];
    const float* ln_s_g   = (const float*)d_in[5];
    const float* ln_s_b   = (const float*)d_in[6];
    const float* ln_m_g   = (const float*)d_in[7];
    const float* ln_m_b   = (const float*)d_in[8];
    const float* mha_in_w = (const float*)d_in[9];
    const float* mha_in_b = (const float*)d_in[10];
    const float* mha_out_w= (const float*)d_in[11];
    const float* mha_out_b= (const float*)d_in[12];
    const float* attn_w1  = (const float*)d_in[13];
    const float* attn_b1  = (const float*)d_in[14];
    const float* attn_w2  = (const float*)d_in[15];
    const float* attn_b2  = (const float*)d_in[16];
    const float* Wq       = (const float*)d_in[17];
    const float* Wk       = (const float*)d_in[18];
    const float* Wv       = (const float*)d_in[19];
    const float* gru_wih  = (const float*)d_in[20];
    const float* gru_whh  = (const float*)d_in[21];
    const float* gru_bih  = (const float*)d_in[22];
    const float* gru_bhh  = (const float*)d_in[23];
    const float* mlp_w1   = (const float*)d_in[24];
    const float* mlp_b1   = (const float*)d_in[25];
    const float* mlp_w2   = (const float*)d_in[26];
    const float* mlp_b2   = (const float*)d_in[27];
    float* out = (float*)d_out;

    char* ws = (char*)d_ws;
    size_t off = 0;
    auto alloc = [&](size_t bytes) -> void* {
        void* p = ws + off;
        off += (bytes + 255) & ~(size_t)255;
        return p;
    };
    unsigned short* Wf    = (unsigned short*)alloc((size_t)256 * 192 * 2);
    float* bias_kv        = (float*)alloc(256 * 4);
    float* Wq_s           = (float*)alloc(128 * 128 * 4);
    float* bias_q         = (float*)alloc(128 * 4);
    unsigned short* k1    = (unsigned short*)alloc((size_t)64 * 4096 * 128 * 2);
    unsigned short* v1T   = (unsigned short*)alloc((size_t)64 * 128 * 4096 * 2);
    float* slotsA         = (float*)alloc((size_t)64 * 11 * 128 * 4);
    float* slotsB         = (float*)alloc((size_t)64 * 11 * 128 * 4);
    float* qbuf           = (float*)alloc((size_t)64 * 11 * 128 * 4);
    float* Upart          = (float*)alloc((size_t)64 * 64 * 11 * 128 * 4);
    float* Spart          = (float*)alloc((size_t)64 * 64 * 11 * 4);
    float* slbuf          = (float*)alloc((size_t)64 * 11 * 128 * 4);
    float* qkvbuf         = (float*)alloc((size_t)64 * 11 * 384 * 4);
    float* updbuf         = (float*)alloc((size_t)64 * 11 * 128 * 4);
    float* Wg             = (float*)alloc((size_t)128 * 768 * 4);
    float* W1t            = (float*)alloc((size_t)128 * 256 * 4);
    float* W2t            = (float*)alloc((size_t)256 * 128 * 4);
    float* Wqt            = (float*)alloc((size_t)128 * 128 * 4);
    (void)ws_size; (void)in_sizes; (void)n_in; (void)out_size;

    k0_prep<<<384, 64, 0, stream>>>(Wk, Wv, ln_in_g, ln_in_b, Wq, ln_s_g, ln_s_b,
                                    Wf, bias_kv, Wq_s, bias_q);
    k0t_prep<<<640, 128, 0, stream>>>(gru_wih, gru_whh, mlp_w1, mlp_w2, Wq, ln_s_g,
                                      Wg, W1t, W2t, Wqt);
    k1_lnproj<<<4096, 512, 0, stream>>>(inputs, Wf, bias_kv, k1, v1T);
    k2a_slots<<<704, 128, 0, stream>>>(islots, ip, ln_s_g, ln_s_b, mha_in_w, mha_in_b,
                                       Wq_s, bias_q, slbuf, qkvbuf, slotsA, qbuf);
    k2b_mha<<<704, 128, 0, stream>>>(ip, qkvbuf, slbuf, mha_out_w, mha_out_b,
                                     attn_w1, attn_b1, attn_w2, attn_b2,
                                     ln_s_g, ln_s_b, Wq_s, bias_q, slotsA, qbuf);
    const float* sprev = slotsA;
    for (int it = 0; it < 2; ++it) {
        k4_attn<<<1024, 256, 0, stream>>>(k1, v1T, qbuf, Upart, Spart);
        kr_reduce<<<704, 256, 0, stream>>>(Upart, Spart, updbuf);
        float* dst = (it == 1) ? out : slotsB;
        k5_gru<<<704, 256, 0, stream>>>(updbuf, sprev, Wg, gru_bih, gru_bhh,
                                        ln_m_g, ln_m_b, W1t, mlp_b1, W2t, mlp_b2,
                                        Wqt, bias_q, dst, qbuf, (it == 0) ? 1 : 0);
        sprev = dst;
    }
}

// Round 16
// 288.784 us; speedup vs baseline: 1.0287x; 1.0287x over previous
//
#include <hip/hip_runtime.h>

typedef __attribute__((ext_vector_type(8))) short short8;
typedef __attribute__((ext_vector_type(4))) float floatx4;

#define B_  64
#define N_  4096
#define DIN 192
#define S_  11
#define E_  128

__device__ inline unsigned short f2bf(float f) {
    union { float f; unsigned u; } v; v.f = f;
    unsigned r = v.u + 0x7FFF + ((v.u >> 16) & 1);
    return (unsigned short)(r >> 16);
}
__device__ inline floatx4 fzero4() { floatx4 v; v[0]=v[1]=v[2]=v[3]=0.f; return v; }
__device__ inline void store_bf4(unsigned short* dst, floatx4 v) {
    union { unsigned short u[4]; unsigned long long q; } o;
    o.u[0] = f2bf(v[0]); o.u[1] = f2bf(v[1]); o.u[2] = f2bf(v[2]); o.u[3] = f2bf(v[3]);
    *(unsigned long long*)dst = o.q;
}
__device__ inline float dot128(const float* __restrict__ w, const float* __restrict__ x) {
    const floatx4* wv = (const floatx4*)w;
    const floatx4* xv = (const floatx4*)x;
    float a = 0.f;
    for (int j = 0; j < 32; ++j) {
        floatx4 w_ = wv[j], x_ = xv[j];
        a += w_[0]*x_[0] + w_[1]*x_[1] + w_[2]*x_[2] + w_[3]*x_[3];
    }
    return a;
}
__device__ inline float dot256(const float* __restrict__ w, const float* __restrict__ x) {
    const floatx4* wv = (const floatx4*)w;
    const floatx4* xv = (const floatx4*)x;
    float a = 0.f;
    for (int j = 0; j < 64; ++j) {
        floatx4 w_ = wv[j], x_ = xv[j];
        a += w_[0]*x_[0] + w_[1]*x_[1] + w_[2]*x_[2] + w_[3]*x_[3];
    }
    return a;
}

// ---------------------------------------------------------------- K0: weight prep (merged k0 + k0t)
__global__ __launch_bounds__(128)
void k0_prep(const float* __restrict__ Wk, const float* __restrict__ Wv,
             const float* __restrict__ ln_in_g, const float* __restrict__ ln_in_b,
             const float* __restrict__ Wq, const float* __restrict__ ln_s_g,
             const float* __restrict__ ln_s_b,
             const float* __restrict__ wih, const float* __restrict__ whh,
             const float* __restrict__ w1, const float* __restrict__ w2,
             unsigned short* __restrict__ Wf, float* __restrict__ bias_kv,
             float* __restrict__ Wq_s, float* __restrict__ bias_q,
             float* __restrict__ Wg, float* __restrict__ W1t,
             float* __restrict__ W2t, float* __restrict__ Wqt) {
    int o = blockIdx.x, t = threadIdx.x;
    const float sc = 0.08838834764831845f;  // 1/sqrt(128)
    if (o < 384) {
        if (t >= 64) return;
        if (o < 256) {
            const float* src = (o < 128) ? (Wk + (size_t)o * DIN) : (Wv + (size_t)(o - 128) * DIN);
            int nt = o >> 4, cc = o & 15;
            float bs = 0.f;
            for (int j = t; j < DIN; j += 64) {
                float w = src[j];
                int kk = j >> 5, gg = (j >> 3) & 3, jj = j & 7;
                Wf[(size_t)(((nt * 6 + kk) << 6) + gg * 16 + cc) * 8 + jj] = f2bf(w * ln_in_g[j]);
                bs += w * ln_in_b[j];
            }
            #pragma unroll
            for (int off = 32; off > 0; off >>= 1) bs += __shfl_down(bs, off);
            if (t == 0) bias_kv[o] = bs;
        } else {
            int e = o - 256;
            float bs = 0.f;
            for (int j = t; j < E_; j += 64) {
                float w = Wq[(size_t)e * E_ + j];
                Wq_s[(size_t)e * E_ + j] = w * ln_s_g[j] * sc;
                bs += w * ln_s_b[j];
            }
            #pragma unroll
            for (int off = 32; off > 0; off >>= 1) bs += __shfl_down(bs, off);
            if (t == 0) bias_q[e] = bs * sc;
        }
    } else {
        int blk = o - 384;
        if (blk < 128) {
            int j = blk;
            for (int oo = t; oo < 768; oo += 128)
                Wg[(size_t)j * 768 + oo] = (oo < 384) ? wih[(size_t)oo * 128 + j]
                                                      : whh[(size_t)(oo - 384) * 128 + j];
        } else if (blk < 256) {
            int j = blk - 128;
            for (int k = t; k < 256; k += 128)
                W1t[(size_t)j * 256 + k] = w1[(size_t)k * 128 + j];
        } else if (blk < 512) {
            int j = blk - 256;
            W2t[(size_t)j * 128 + t] = w2[(size_t)t * 256 + j];
        } else {
            int j = blk - 512;
            Wqt[(size_t)j * 128 + t] = Wq[(size_t)t * 128 + j] * ln_s_g[j] * sc;
        }
    }
}

// ---------------------------------------------------------------- K1: LN + K/V projection (M=64)
__global__ __launch_bounds__(512, 2)
void k1_lnproj(const float* __restrict__ inp, const unsigned short* __restrict__ Wf,
               const float* __restrict__ bias_kv,
               unsigned short* __restrict__ k1o, unsigned short* __restrict__ v1T) {
    __shared__ short8 Al[4 * 6 * 64];   // 24 KB: [rg][kk][lane]
    int t = threadIdx.x, lane = t & 63, wid = t >> 6;
    long rowbase = (long)blockIdx.x * 64;
    int bb = (int)(rowbase >> 12);
    int nbase = (int)(rowbase & 4095);
    int c = lane & 15, g = lane >> 4;
    int nt0 = wid * 2;

    short8 wf[2][6];
    #pragma unroll
    for (int p = 0; p < 2; ++p)
        #pragma unroll
        for (int kk = 0; kk < 6; ++kk)
            wf[p][kk] = *(const short8*)(Wf + (size_t)(((nt0 + p) * 6 + kk) * 64 + lane) * 8);

    if (wid < 4) {
        long row = rowbase + wid * 16 + c;
        const float* rp = inp + row * DIN;
        floatx4 x[12];
        #pragma unroll
        for (int kk = 0; kk < 6; ++kk) {
            x[2 * kk]     = *(const floatx4*)(rp + kk * 32 + g * 8);
            x[2 * kk + 1] = *(const floatx4*)(rp + kk * 32 + g * 8 + 4);
        }
        float s1 = 0.f, s2 = 0.f;
        #pragma unroll
        for (int j = 0; j < 12; ++j)
            #pragma unroll
            for (int e = 0; e < 4; ++e) { s1 += x[j][e]; s2 += x[j][e] * x[j][e]; }
        s1 += __shfl_xor(s1, 16); s1 += __shfl_xor(s1, 32);
        s2 += __shfl_xor(s2, 16); s2 += __shfl_xor(s2, 32);
        float mean = s1 * (1.f / 192.f);
        float var  = s2 * (1.f / 192.f) - mean * mean;
        float rsd  = rsqrtf(var + 1e-5f);
        #pragma unroll
        for (int kk = 0; kk < 6; ++kk) {
            short8 f;
            #pragma unroll
            for (int e = 0; e < 4; ++e) {
                f[e]     = (short)f2bf((x[2 * kk][e]     - mean) * rsd);
                f[4 + e] = (short)f2bf((x[2 * kk + 1][e] - mean) * rsd);
            }
            Al[(wid * 6 + kk) * 64 + lane] = f;
        }
    }
    __syncthreads();

    floatx4 acc[2][4];
    #pragma unroll
    for (int p = 0; p < 2; ++p)
        #pragma unroll
        for (int rg = 0; rg < 4; ++rg) acc[p][rg] = fzero4();

    if (wid < 4) {
        #pragma unroll
        for (int rg = 0; rg < 4; ++rg)
            #pragma unroll
            for (int kk = 0; kk < 6; ++kk) {
                short8 a = Al[(rg * 6 + kk) * 64 + lane];
                acc[0][rg] = __builtin_amdgcn_mfma_f32_16x16x32_bf16(wf[0][kk], a, acc[0][rg], 0, 0, 0);
                acc[1][rg] = __builtin_amdgcn_mfma_f32_16x16x32_bf16(wf[1][kk], a, acc[1][rg], 0, 0, 0);
            }
        #pragma unroll
        for (int p = 0; p < 2; ++p) {
            int nt = nt0 + p;
            floatx4 bia = *(const floatx4*)(bias_kv + nt * 16 + g * 4);
            #pragma unroll
            for (int rg = 0; rg < 4; ++rg) {
                floatx4 vv;
                #pragma unroll
                for (int r = 0; r < 4; ++r) vv[r] = acc[p][rg][r] + bia[r];
                store_bf4(k1o + (size_t)(rowbase + rg * 16 + c) * 128 + nt * 16 + g * 4, vv);
            }
        }
    } else {
        #pragma unroll
        for (int rg = 0; rg < 4; ++rg)
            #pragma unroll
            for (int kk = 0; kk < 6; ++kk) {
                short8 a = Al[(rg * 6 + kk) * 64 + lane];
                acc[0][rg] = __builtin_amdgcn_mfma_f32_16x16x32_bf16(a, wf[0][kk], acc[0][rg], 0, 0, 0);
                acc[1][rg] = __builtin_amdgcn_mfma_f32_16x16x32_bf16(a, wf[1][kk], acc[1][rg], 0, 0, 0);
            }
        #pragma unroll
        for (int p = 0; p < 2; ++p) {
            int d = (nt0 + p - 8) * 16 + c;
            float bia = bias_kv[128 + d];
            size_t base = (((size_t)bb * 128 + d) << 12) + nbase;
            #pragma unroll
            for (int rg = 0; rg < 4; ++rg) {
                floatx4 vv;
                #pragma unroll
                for (int r = 0; r < 4; ++r) vv[r] = acc[p][rg][r] + bia;
                store_bf4(v1T + base + rg * 16 + g * 4, vv);
            }
        }
    }
}

// ---------------------------------------------------------------- K2a: LN(islots) + qkv projection (per b,s)
__global__ __launch_bounds__(128)
void k2a_slots(const float* __restrict__ islots, const int* __restrict__ ip,
               const float* __restrict__ ln_s_g, const float* __restrict__ ln_s_b,
               const float* __restrict__ in_w, const float* __restrict__ in_b,
               const float* __restrict__ Wq_s, const float* __restrict__ bias_q,
               float* __restrict__ slbuf, float* __restrict__ qkvbuf,
               float* __restrict__ slotsA, float* __restrict__ qbuf) {
    __shared__ float sl[128];
    __shared__ float sn[128];
    __shared__ float red[4];
    int t = threadIdx.x;
    size_t bs = blockIdx.x;
    float x = islots[bs * 128 + t];
    float s1 = x, s2 = x * x;
    #pragma unroll
    for (int off = 32; off > 0; off >>= 1) { s1 += __shfl_xor(s1, off); s2 += __shfl_xor(s2, off); }
    if ((t & 63) == 0) { red[(t >> 6) * 2] = s1; red[(t >> 6) * 2 + 1] = s2; }
    __syncthreads();
    float tot1 = red[0] + red[2], tot2 = red[1] + red[3];
    float mean = tot1 * (1.f / 128.f), var = tot2 * (1.f / 128.f) - mean * mean;
    float rs = rsqrtf(var + 1e-5f);
    float slv = (x - mean) * rs * ln_s_g[t] + ln_s_b[t];
    sl[t] = slv;
    slbuf[bs * 128 + t] = slv;
    __syncthreads();
    int ival = *ip;
    if (ival != 1) {
        #pragma unroll
        for (int kI = 0; kI < 3; ++kI) {
            int e = t + kI * 128;
            qkvbuf[bs * 384 + e] = dot128(in_w + (size_t)e * 128, sl) + in_b[e];
        }
    } else {
        slotsA[bs * 128 + t] = slv;
        float q1 = slv, q2 = slv * slv;
        #pragma unroll
        for (int off = 32; off > 0; off >>= 1) { q1 += __shfl_xor(q1, off); q2 += __shfl_xor(q2, off); }
        __syncthreads();
        if ((t & 63) == 0) { red[(t >> 6) * 2] = q1; red[(t >> 6) * 2 + 1] = q2; }
        __syncthreads();
        float qt1 = red[0] + red[2], qt2 = red[1] + red[3];
        float qmean = qt1 * (1.f / 128.f), qvar = qt2 * (1.f / 128.f) - qmean * qmean;
        float qrs = rsqrtf(qvar + 1e-5f);
        sn[t] = (slv - qmean) * qrs;
        __syncthreads();
        qbuf[bs * 128 + t] = dot128(Wq_s + (size_t)t * 128, sn) + bias_q[t];
    }
}

// ---------------------------------------------------------------- K2b: MHA + MLP + q (per b,s)
__global__ __launch_bounds__(128)
void k2b_mha(const int* __restrict__ ip, const float* __restrict__ qkvbuf,
             const float* __restrict__ slbuf,
             const float* __restrict__ out_w, const float* __restrict__ out_b,
             const float* __restrict__ w1, const float* __restrict__ b1,
             const float* __restrict__ w2, const float* __restrict__ b2,
             const float* __restrict__ ln_s_g, const float* __restrict__ ln_s_b,
             const float* __restrict__ Wq_s, const float* __restrict__ bias_q,
             float* __restrict__ slotsA, float* __restrict__ qbuf) {
    if (*ip == 1) return;
    __shared__ float qv[128];
    __shared__ float att[4][12];
    __shared__ float oh[128];
    __shared__ float s3[128];
    __shared__ float h1[256];
    __shared__ float sn[128];
    __shared__ float red[4];
    int t = threadIdx.x;
    int bb = blockIdx.x / 11, s = blockIdx.x % 11;
    size_t base = (size_t)bb * 11;
    qv[t] = qkvbuf[(base + s) * 384 + t];
    __syncthreads();
    if (t < 44) {
        int h = t / 11, j = t % 11;
        const float* kr = qkvbuf + (base + j) * 384 + 128 + h * 32;
        const float* qr = &qv[h * 32];
        float a = 0.f;
        #pragma unroll
        for (int d = 0; d < 32; ++d) a += qr[d] * kr[d];
        att[h][j] = a * 0.17677669529663687f;
    }
    __syncthreads();
    if (t < 4) {
        float mx = -1e30f;
        #pragma unroll
        for (int j = 0; j < 11; ++j) mx = fmaxf(mx, att[t][j]);
        float sum = 0.f, e_[11];
        #pragma unroll
        for (int j = 0; j < 11; ++j) { e_[j] = __expf(att[t][j] - mx); sum += e_[j]; }
        float inv = 1.f / sum;
        #pragma unroll
        for (int j = 0; j < 11; ++j) att[t][j] = e_[j] * inv;
    }
    __syncthreads();
    {
        int h = t >> 5;
        float a = 0.f;
        #pragma unroll
        for (int j = 0; j < 11; ++j) a += att[h][j] * qkvbuf[(base + j) * 384 + 256 + t];
        oh[t] = a;
    }
    __syncthreads();
    float slv = slbuf[(base + s) * 128 + t];
    float s2v = slv + dot128(out_w + (size_t)t * 128, oh) + out_b[t];
    float s1 = s2v, s2 = s2v * s2v;
    #pragma unroll
    for (int off = 32; off > 0; off >>= 1) { s1 += __shfl_xor(s1, off); s2 += __shfl_xor(s2, off); }
    if ((t & 63) == 0) { red[(t >> 6) * 2] = s1; red[(t >> 6) * 2 + 1] = s2; }
    __syncthreads();
    float tot1 = red[0] + red[2], tot2 = red[1] + red[3];
    float mean = tot1 * (1.f / 128.f), var = tot2 * (1.f / 128.f) - mean * mean;
    float rs = rsqrtf(var + 1e-5f);
    float s3v = (s2v - mean) * rs * ln_s_g[t] + ln_s_b[t];
    s3[t] = s3v;
    __syncthreads();
    #pragma unroll
    for (int kI = 0; kI < 2; ++kI) {
        int k = t + kI * 128;
        float a = dot128(w1 + (size_t)k * 128, s3) + b1[k];
        h1[k] = a > 0.f ? a : 0.f;
    }
    __syncthreads();
    float fin = s3v + dot256(w2 + (size_t)t * 256, h1) + b2[t];
    slotsA[(base + s) * 128 + t] = fin;
    float q1 = fin, q2 = fin * fin;
    #pragma unroll
    for (int off = 32; off > 0; off >>= 1) { q1 += __shfl_xor(q1, off); q2 += __shfl_xor(q2, off); }
    __syncthreads();
    if ((t & 63) == 0) { red[(t >> 6) * 2] = q1; red[(t >> 6) * 2 + 1] = q2; }
    __syncthreads();
    float qt1 = red[0] + red[2], qt2 = red[1] + red[3];
    float qmean = qt1 * (1.f / 128.f), qvar = qt2 * (1.f / 128.f) - qmean * qmean;
    float qrs = rsqrtf(qvar + 1e-5f);
    sn[t] = (fin - qmean) * qrs;
    __syncthreads();
    qbuf[(base + s) * 128 + t] = dot128(Wq_s + (size_t)t * 128, sn) + bias_q[t];
}

// ---------------------------------------------------------------- K4: slot attention main (barrier-free, per-wave partials)
#define LGP 13
#define PPAD 72
struct K4Arena {
    float Lg[64][LGP];            // 3328 B
    unsigned short Pl[16][PPAD];  // 2304 B
};
__global__ __launch_bounds__(256)
void k4_attn(const unsigned short* __restrict__ k1, const unsigned short* __restrict__ v1T,
             const float* __restrict__ qbuf, float* __restrict__ Upart, float* __restrict__ Spart) {
    __shared__ K4Arena ar[4];   // 22528 B
    int t = threadIdx.x, lane = t & 63, wid = t >> 6;
    int bb = blockIdx.x >> 4;
    int part = blockIdx.x & 15;
    int n0 = part * 256 + wid * 64;
    int pidx = part * 4 + wid;   // 64 partials per batch
    int c = lane & 15, g = lane >> 4;
    K4Arena& A = ar[wid];

    short8 bq[4];
    #pragma unroll
    for (int kk = 0; kk < 4; ++kk) {
        short8 f;
        if (c < 11) {
            const floatx4* qp = (const floatx4*)(qbuf + ((size_t)bb * 11 + c) * 128 + kk * 32 + g * 8);
            floatx4 q0 = qp[0], q1 = qp[1];
            #pragma unroll
            for (int e = 0; e < 4; ++e) { f[e] = (short)f2bf(q0[e]); f[4 + e] = (short)f2bf(q1[e]); }
        } else {
            #pragma unroll
            for (int e = 0; e < 8; ++e) f[e] = 0;
        }
        bq[kk] = f;
    }

    floatx4 lac[4];
    #pragma unroll
    for (int t4 = 0; t4 < 4; ++t4) {
        lac[t4] = fzero4();
        #pragma unroll
        for (int kk = 0; kk < 4; ++kk) {
            const short8* ap = (const short8*)(k1 + ((size_t)bb * 4096 + n0 + t4 * 16 + c) * 128 + kk * 32 + g * 8);
            lac[t4] = __builtin_amdgcn_mfma_f32_16x16x32_bf16(*ap, bq[kk], lac[t4], 0, 0, 0);
        }
    }
    if (c < LGP) {
        #pragma unroll
        for (int t4 = 0; t4 < 4; ++t4)
            #pragma unroll
            for (int r = 0; r < 4; ++r)
                A.Lg[t4 * 16 + g * 4 + r][c] = lac[t4][r];
    }

    float p[11];
    {
        float mx = -1e30f;
        #pragma unroll
        for (int s = 0; s < 11; ++s) { p[s] = A.Lg[lane][s]; mx = fmaxf(mx, p[s]); }
        float sum = 0.f;
        #pragma unroll
        for (int s = 0; s < 11; ++s) { p[s] = __expf(p[s] - mx); sum += p[s]; }
        float inv = 1.f / sum;
        #pragma unroll
        for (int s = 0; s < 11; ++s) p[s] = p[s] * inv + 1e-8f;
    }
    #pragma unroll
    for (int s = 0; s < 11; ++s) A.Pl[s][lane] = f2bf(p[s]);

    floatx4 uac[8];
    floatx4 sac = fzero4();
    #pragma unroll
    for (int dt = 0; dt < 8; ++dt) uac[dt] = fzero4();
    short8 ones;
    #pragma unroll
    for (int e = 0; e < 8; ++e) ones[e] = (short)0x3F80;
    #pragma unroll
    for (int kk = 0; kk < 2; ++kk) {
        short8 ap = *(const short8*)(&A.Pl[c][kk * 32 + g * 8]);
        #pragma unroll
        for (int dt = 0; dt < 8; ++dt) {
            const short8* vp = (const short8*)(v1T + ((size_t)bb * 128 + dt * 16 + c) * 4096 + n0 + kk * 32 + g * 8);
            uac[dt] = __builtin_amdgcn_mfma_f32_16x16x32_bf16(ap, *vp, uac[dt], 0, 0, 0);
        }
        sac = __builtin_amdgcn_mfma_f32_16x16x32_bf16(ap, ones, sac, 0, 0, 0);
    }
    size_t ub = ((size_t)bb * 64 + pidx) * 11;
    #pragma unroll
    for (int r = 0; r < 4; ++r) {
        int s = g * 4 + r;
        if (s < 11) {
            #pragma unroll
            for (int dt = 0; dt < 8; ++dt)
                Upart[(ub + s) * 128 + dt * 16 + c] = uac[dt][r];
            if (c == 0) Spart[ub + s] = sac[r];
        }
    }
}

// ---------------------------------------------------------------- K5: reduce partials + GRU + LN + MLP (+ q)
__global__ __launch_bounds__(256)
void k5_gru(const float* __restrict__ Upart, const float* __restrict__ Spart,
            const float* __restrict__ slots_prev,
            const float* __restrict__ Wg,
            const float* __restrict__ bih, const float* __restrict__ bhh,
            const float* __restrict__ ln_m_g, const float* __restrict__ ln_m_b,
            const float* __restrict__ W1t, const float* __restrict__ b1,
            const float* __restrict__ W2t, const float* __restrict__ b2,
            const float* __restrict__ Wqt, const float* __restrict__ bias_q,
            float* __restrict__ out, float* __restrict__ qbuf, int compute_q) {
    __shared__ float updp[8][128];
    __shared__ float redS;
    __shared__ float upd[128];
    __shared__ float sp[128];
    __shared__ float gL[768];
    __shared__ float nsb[128];
    __shared__ float mrow[128];
    __shared__ float hrow[256];
    __shared__ float part2[2][128];
    __shared__ float red[4];
    __shared__ float snq[128];
    int t = threadIdx.x;
    int bb = blockIdx.x / 11, s = blockIdx.x % 11;
    size_t rowoff = ((size_t)bb * 11 + s) * 128;

    // ---- kr front-end: reduce 64 partials
    {
        int p = t >> 5, c4 = t & 31;
        size_t base = ((size_t)bb * 704 + s) * 128;
        floatx4 acc = fzero4();
        #pragma unroll
        for (int i = 0; i < 8; ++i) {
            const floatx4* rp = (const floatx4*)(Upart + base + (size_t)(p * 8 + i) * 1408);
            acc += rp[c4];
        }
        *(floatx4*)&updp[p][c4 * 4] = acc;
    }
    if (t < 64) {
        float sa = Spart[(size_t)bb * 704 + (size_t)t * 11 + s];
        #pragma unroll
        for (int off = 32; off > 0; off >>= 1) sa += __shfl_xor(sa, off);
        if (t == 0) redS = sa;
    }
    if (t < 128) sp[t] = slots_prev[rowoff + t];
    __syncthreads();
    if (t < 128) {
        float ua = 0.f;
        #pragma unroll
        for (int p = 0; p < 8; ++p) ua += updp[p][t];
        upd[t] = ua / redS;
    }
    __syncthreads();

    // ---- gates (j-outer coalesced)
    {
        const float* x1 = (t < 128) ? upd : sp;
        float a0 = 0.f, a1 = 0.f, a2 = 0.f;
        for (int j = 0; j < 128; ++j) {
            const float* wr = Wg + (size_t)j * 768;
            float xu = upd[j], xs = sp[j];
            a0 = fmaf(wr[t],       xu,    a0);
            a1 = fmaf(wr[t + 256], x1[j], a1);
            a2 = fmaf(wr[t + 512], xs,    a2);
        }
        float b0 = bih[t];
        float b1g = (t < 128) ? bih[t + 256] : bhh[t - 128];
        float b2g = bhh[t + 128];
        gL[t]       = a0 + b0;
        gL[t + 256] = a1 + b1g;
        gL[t + 512] = a2 + b2g;
    }
    __syncthreads();
    if (t < 128) {
        float r = 1.f / (1.f + __expf(-(gL[t] + gL[384 + t])));
        float z = 1.f / (1.f + __expf(-(gL[128 + t] + gL[512 + t])));
        float nn = tanhf(gL[256 + t] + r * gL[640 + t]);
        float ns = (1.f - z) * nn + z * sp[t];
        nsb[t] = ns;
        float s1 = ns, s2 = ns * ns;
        #pragma unroll
        for (int off = 32; off > 0; off >>= 1) { s1 += __shfl_xor(s1, off); s2 += __shfl_xor(s2, off); }
        if ((t & 63) == 0) { red[(t >> 6) * 2] = s1; red[(t >> 6) * 2 + 1] = s2; }
    }
    __syncthreads();
    if (t < 128) {
        float tot1 = red[0] + red[2], tot2 = red[1] + red[3];
        float mean = tot1 * (1.f / 128.f), var = tot2 * (1.f / 128.f) - mean * mean;
        float rs = rsqrtf(var + 1e-5f);
        mrow[t] = (nsb[t] - mean) * rs * ln_m_g[t] + ln_m_b[t];
    }
    __syncthreads();
    {
        float a = 0.f;
        for (int j = 0; j < 128; ++j) a = fmaf(W1t[(size_t)j * 256 + t], mrow[j], a);
        a += b1[t];
        hrow[t] = a > 0.f ? a : 0.f;
    }
    __syncthreads();
    {
        int half = t >> 7, e = t & 127;
        float a = 0.f;
        for (int j = 0; j < 128; ++j)
            a = fmaf(W2t[(size_t)(half * 128 + j) * 128 + e], hrow[half * 128 + j], a);
        part2[half][e] = a;
    }
    __syncthreads();
    float val = 0.f;
    if (t < 128) {
        val = nsb[t] + part2[0][t] + part2[1][t] + b2[t];
        out[rowoff + t] = val;
    }
    if (!compute_q) return;
    __syncthreads();
    if (t < 128) {
        float q1 = val, q2 = val * val;
        #pragma unroll
        for (int off = 32; off > 0; off >>= 1) { q1 += __shfl_xor(q1, off); q2 += __shfl_xor(q2, off); }
        if ((t & 63) == 0) { red[(t >> 6) * 2] = q1; red[(t >> 6) * 2 + 1] = q2; }
    }
    __syncthreads();
    if (t < 128) {
        float qt1 = red[0] + red[2], qt2 = red[1] + red[3];
        float qmean = qt1 * (1.f / 128.f), qvar = qt2 * (1.f / 128.f) - qmean * qmean;
        float qrs = rsqrtf(qvar + 1e-5f);
        snq[t] = (val - qmean) * qrs;
    }
    __syncthreads();
    {
        int half = t >> 7, e = t & 127;
        float a = 0.f;
        for (int j = 0; j < 64; ++j)
            a = fmaf(Wqt[(size_t)(half * 64 + j) * 128 + e], snq[half * 64 + j], a);
        part2[half][e] = a;
    }
    __syncthreads();
    if (t < 128)
        qbuf[rowoff + t] = part2[0][t] + part2[1][t] + bias_q[t];
}

// ---------------------------------------------------------------- host
extern "C" void kernel_launch(void* const* d_in, const int* in_sizes, int n_in,
                              void* d_out, int out_size, void* d_ws, size_t ws_size,
                              hipStream_t stream) {
    const float* inputs   = (const float*)d_in[0];
    const float* islots   = (const float*)d_in[1];
    const int*   ip       = (const int*)d_in[2];
    const float* ln_in_g  = (const float*)d_in[3];
    const float* ln_in_b  = (const float*)d_in[4];
    const float* ln_s_g   = (const float*)d_in[5];
    const float* ln_s_b   = (const float*)d_in[6];
    const float* ln_m_g   = (const float*)d_in[7];
    const float* ln_m_b   = (const float*)d_in[8];
    const float* mha_in_w = (const float*)d_in[9];
    const float* mha_in_b = (const float*)d_in[10];
    const float* mha_out_w= (const float*)d_in[11];
    const float* mha_out_b= (const float*)d_in[12];
    const float* attn_w1  = (const float*)d_in[13];
    const float* attn_b1  = (const float*)d_in[14];
    const float* attn_w2  = (const float*)d_in[15];
    const float* attn_b2  = (const float*)d_in[16];
    const float* Wq       = (const float*)d_in[17];
    const float* Wk       = (const float*)d_in[18];
    const float* Wv       = (const float*)d_in[19];
    const float* gru_wih  = (const float*)d_in[20];
    const float* gru_whh  = (const float*)d_in[21];
    const float* gru_bih  = (const float*)d_in[22];
    const float* gru_bhh  = (const float*)d_in[23];
    const float* mlp_w1   = (const float*)d_in[24];
    const float* mlp_b1   = (const float*)d_in[25];
    const float* mlp_w2   = (const float*)d_in[26];
    const float* mlp_b2   = (const float*)d_in[27];
    float* out = (float*)d_out;

    char* ws = (char*)d_ws;
    size_t off = 0;
    auto alloc = [&](size_t bytes) -> void* {
        void* p = ws + off;
        off += (bytes + 255) & ~(size_t)255;
        return p;
    };
    unsigned short* Wf    = (unsigned short*)alloc((size_t)256 * 192 * 2);
    float* bias_kv        = (float*)alloc(256 * 4);
    float* Wq_s           = (float*)alloc(128 * 128 * 4);
    float* bias_q         = (float*)alloc(128 * 4);
    unsigned short* k1    = (unsigned short*)alloc((size_t)64 * 4096 * 128 * 2);
    unsigned short* v1T   = (unsigned short*)alloc((size_t)64 * 128 * 4096 * 2);
    float* slotsA         = (float*)alloc((size_t)64 * 11 * 128 * 4);
    float* slotsB         = (float*)alloc((size_t)64 * 11 * 128 * 4);
    float* qbuf           = (float*)alloc((size_t)64 * 11 * 128 * 4);
    float* Upart          = (float*)alloc((size_t)64 * 64 * 11 * 128 * 4);
    float* Spart          = (float*)alloc((size_t)64 * 64 * 11 * 4);
    float* slbuf          = (float*)alloc((size_t)64 * 11 * 128 * 4);
    float* qkvbuf         = (float*)alloc((size_t)64 * 11 * 384 * 4);
    float* Wg             = (float*)alloc((size_t)128 * 768 * 4);
    float* W1t            = (float*)alloc((size_t)128 * 256 * 4);
    float* W2t            = (float*)alloc((size_t)256 * 128 * 4);
    float* Wqt            = (float*)alloc((size_t)128 * 128 * 4);
    (void)ws_size; (void)in_sizes; (void)n_in; (void)out_size;

    k0_prep<<<1024, 128, 0, stream>>>(Wk, Wv, ln_in_g, ln_in_b, Wq, ln_s_g, ln_s_b,
                                      gru_wih, gru_whh, mlp_w1, mlp_w2,
                                      Wf, bias_kv, Wq_s, bias_q, Wg, W1t, W2t, Wqt);
    k1_lnproj<<<4096, 512, 0, stream>>>(inputs, Wf, bias_kv, k1, v1T);
    k2a_slots<<<704, 128, 0, stream>>>(islots, ip, ln_s_g, ln_s_b, mha_in_w, mha_in_b,
                                       Wq_s, bias_q, slbuf, qkvbuf, slotsA, qbuf);
    k2b_mha<<<704, 128, 0, stream>>>(ip, qkvbuf, slbuf, mha_out_w, mha_out_b,
                                     attn_w1, attn_b1, attn_w2, attn_b2,
                                     ln_s_g, ln_s_b, Wq_s, bias_q, slotsA, qbuf);
    const float* sprev = slotsA;
    for (int it = 0; it < 2; ++it) {
        k4_attn<<<1024, 256, 0, stream>>>(k1, v1T, qbuf, Upart, Spart);
        float* dst = (it == 1) ? out : slotsB;
        k5_gru<<<704, 256, 0, stream>>>(Upart, Spart, sprev, Wg, gru_bih, gru_bhh,
                                        ln_m_g, ln_m_b, W1t, mlp_b1, W2t, mlp_b2,
                                        Wqt, bias_q, dst, qbuf, (it == 0) ? 1 : 0);
        sprev = dst;
    }
}

// Round 17
// 283.411 us; speedup vs baseline: 1.0482x; 1.0190x over previous
//
#include <hip/hip_runtime.h>

typedef __attribute__((ext_vector_type(8))) short short8;
typedef __attribute__((ext_vector_type(4))) float floatx4;

#define B_  64
#define N_  4096
#define DIN 192
#define S_  11
#define E_  128

__device__ inline unsigned short f2bf(float f) {
    union { float f; unsigned u; } v; v.f = f;
    unsigned r = v.u + 0x7FFF + ((v.u >> 16) & 1);
    return (unsigned short)(r >> 16);
}
__device__ inline floatx4 fzero4() { floatx4 v; v[0]=v[1]=v[2]=v[3]=0.f; return v; }
__device__ inline void store_bf4(unsigned short* dst, floatx4 v) {
    union { unsigned short u[4]; unsigned long long q; } o;
    o.u[0] = f2bf(v[0]); o.u[1] = f2bf(v[1]); o.u[2] = f2bf(v[2]); o.u[3] = f2bf(v[3]);
    *(unsigned long long*)dst = o.q;
}
__device__ inline float dot128(const float* __restrict__ w, const float* __restrict__ x) {
    const floatx4* wv = (const floatx4*)w;
    const floatx4* xv = (const floatx4*)x;
    float a = 0.f;
    for (int j = 0; j < 32; ++j) {
        floatx4 w_ = wv[j], x_ = xv[j];
        a += w_[0]*x_[0] + w_[1]*x_[1] + w_[2]*x_[2] + w_[3]*x_[3];
    }
    return a;
}
__device__ inline float dot256(const float* __restrict__ w, const float* __restrict__ x) {
    const floatx4* wv = (const floatx4*)w;
    const floatx4* xv = (const floatx4*)x;
    float a = 0.f;
    for (int j = 0; j < 64; ++j) {
        floatx4 w_ = wv[j], x_ = xv[j];
        a += w_[0]*x_[0] + w_[1]*x_[1] + w_[2]*x_[2] + w_[3]*x_[3];
    }
    return a;
}

// ---------------------------------------------------------------- K0: weight prep (merged k0 + k0t)
__global__ __launch_bounds__(128)
void k0_prep(const float* __restrict__ Wk, const float* __restrict__ Wv,
             const float* __restrict__ ln_in_g, const float* __restrict__ ln_in_b,
             const float* __restrict__ Wq, const float* __restrict__ ln_s_g,
             const float* __restrict__ ln_s_b,
             const float* __restrict__ wih, const float* __restrict__ whh,
             const float* __restrict__ w1, const float* __restrict__ w2,
             unsigned short* __restrict__ Wf, float* __restrict__ bias_kv,
             float* __restrict__ Wq_s, float* __restrict__ bias_q,
             float* __restrict__ Wg, float* __restrict__ W1t,
             float* __restrict__ W2t, float* __restrict__ Wqt) {
    int o = blockIdx.x, t = threadIdx.x;
    const float sc = 0.08838834764831845f;  // 1/sqrt(128)
    if (o < 384) {
        if (t >= 64) return;
        if (o < 256) {
            const float* src = (o < 128) ? (Wk + (size_t)o * DIN) : (Wv + (size_t)(o - 128) * DIN);
            int nt = o >> 4, cc = o & 15;
            float bs = 0.f;
            for (int j = t; j < DIN; j += 64) {
                float w = src[j];
                int kk = j >> 5, gg = (j >> 3) & 3, jj = j & 7;
                Wf[(size_t)(((nt * 6 + kk) << 6) + gg * 16 + cc) * 8 + jj] = f2bf(w * ln_in_g[j]);
                bs += w * ln_in_b[j];
            }
            #pragma unroll
            for (int off = 32; off > 0; off >>= 1) bs += __shfl_down(bs, off);
            if (t == 0) bias_kv[o] = bs;
        } else {
            int e = o - 256;
            float bs = 0.f;
            for (int j = t; j < E_; j += 64) {
                float w = Wq[(size_t)e * E_ + j];
                Wq_s[(size_t)e * E_ + j] = w * ln_s_g[j] * sc;
                bs += w * ln_s_b[j];
            }
            #pragma unroll
            for (int off = 32; off > 0; off >>= 1) bs += __shfl_down(bs, off);
            if (t == 0) bias_q[e] = bs * sc;
        }
    } else {
        int blk = o - 384;
        if (blk < 128) {
            int j = blk;
            for (int oo = t; oo < 768; oo += 128)
                Wg[(size_t)j * 768 + oo] = (oo < 384) ? wih[(size_t)oo * 128 + j]
                                                      : whh[(size_t)(oo - 384) * 128 + j];
        } else if (blk < 256) {
            int j = blk - 128;
            for (int k = t; k < 256; k += 128)
                W1t[(size_t)j * 256 + k] = w1[(size_t)k * 128 + j];
        } else if (blk < 512) {
            int j = blk - 256;
            W2t[(size_t)j * 128 + t] = w2[(size_t)t * 256 + j];
        } else {
            int j = blk - 512;
            Wqt[(size_t)j * 128 + t] = Wq[(size_t)t * 128 + j] * ln_s_g[j] * sc;
        }
    }
}

// ---------------------------------------------------------------- K1: LN + K/V projection (M=64, all-wave staging)
__global__ __launch_bounds__(512, 2)
void k1_lnproj(const float* __restrict__ inp, const unsigned short* __restrict__ Wf,
               const float* __restrict__ bias_kv,
               unsigned short* __restrict__ k1o, unsigned short* __restrict__ v1T) {
    __shared__ short8 Al[4 * 6 * 64];   // 24 KB: [rg][kk][(g,c)]
    int t = threadIdx.x, lane = t & 63, wid = t >> 6;
    long rowbase = (long)blockIdx.x * 64;
    int bb = (int)(rowbase >> 12);
    int nbase = (int)(rowbase & 4095);
    int c = lane & 15, g = lane >> 4;
    int nt0 = wid * 2;

    short8 wf[2][6];
    #pragma unroll
    for (int p = 0; p < 2; ++p)
        #pragma unroll
        for (int kk = 0; kk < 6; ++kk)
            wf[p][kk] = *(const short8*)(Wf + (size_t)(((nt0 + p) * 6 + kk) * 64 + lane) * 8);

    // ---- all-wave staging: thread t -> row r = t>>3, chunk q = t&7 (24 floats = 3 fragments)
    {
        int r = t >> 3, q = t & 7;
        const float* rp = inp + (rowbase + r) * DIN + q * 24;
        floatx4 x[6];
        #pragma unroll
        for (int i = 0; i < 6; ++i) x[i] = *(const floatx4*)(rp + i * 4);
        float s1 = 0.f, s2 = 0.f;
        #pragma unroll
        for (int i = 0; i < 6; ++i)
            #pragma unroll
            for (int e = 0; e < 4; ++e) { s1 += x[i][e]; s2 += x[i][e] * x[i][e]; }
        s1 += __shfl_xor(s1, 1); s1 += __shfl_xor(s1, 2); s1 += __shfl_xor(s1, 4);
        s2 += __shfl_xor(s2, 1); s2 += __shfl_xor(s2, 2); s2 += __shfl_xor(s2, 4);
        float mean = s1 * (1.f / 192.f);
        float var  = s2 * (1.f / 192.f) - mean * mean;
        float rsd  = rsqrtf(var + 1e-5f);
        int rg = r >> 4, cc = r & 15;
        #pragma unroll
        for (int f = 0; f < 3; ++f) {
            int F = q * 3 + f;          // fragment group 0..23
            int kk = F >> 2, gg = F & 3;
            short8 w;
            #pragma unroll
            for (int e = 0; e < 4; ++e) {
                w[e]     = (short)f2bf((x[2 * f][e]     - mean) * rsd);
                w[4 + e] = (short)f2bf((x[2 * f + 1][e] - mean) * rsd);
            }
            Al[(rg * 6 + kk) * 64 + gg * 16 + cc] = w;
        }
    }
    __syncthreads();

    floatx4 acc[2][4];
    #pragma unroll
    for (int p = 0; p < 2; ++p)
        #pragma unroll
        for (int rg = 0; rg < 4; ++rg) acc[p][rg] = fzero4();

    if (wid < 4) {
        #pragma unroll
        for (int rg = 0; rg < 4; ++rg)
            #pragma unroll
            for (int kk = 0; kk < 6; ++kk) {
                short8 a = Al[(rg * 6 + kk) * 64 + lane];
                acc[0][rg] = __builtin_amdgcn_mfma_f32_16x16x32_bf16(wf[0][kk], a, acc[0][rg], 0, 0, 0);
                acc[1][rg] = __builtin_amdgcn_mfma_f32_16x16x32_bf16(wf[1][kk], a, acc[1][rg], 0, 0, 0);
            }
        #pragma unroll
        for (int p = 0; p < 2; ++p) {
            int nt = nt0 + p;
            floatx4 bia = *(const floatx4*)(bias_kv + nt * 16 + g * 4);
            #pragma unroll
            for (int rg = 0; rg < 4; ++rg) {
                floatx4 vv;
                #pragma unroll
                for (int r = 0; r < 4; ++r) vv[r] = acc[p][rg][r] + bia[r];
                store_bf4(k1o + (size_t)(rowbase + rg * 16 + c) * 128 + nt * 16 + g * 4, vv);
            }
        }
    } else {
        #pragma unroll
        for (int rg = 0; rg < 4; ++rg)
            #pragma unroll
            for (int kk = 0; kk < 6; ++kk) {
                short8 a = Al[(rg * 6 + kk) * 64 + lane];
                acc[0][rg] = __builtin_amdgcn_mfma_f32_16x16x32_bf16(a, wf[0][kk], acc[0][rg], 0, 0, 0);
                acc[1][rg] = __builtin_amdgcn_mfma_f32_16x16x32_bf16(a, wf[1][kk], acc[1][rg], 0, 0, 0);
            }
        #pragma unroll
        for (int p = 0; p < 2; ++p) {
            int d = (nt0 + p - 8) * 16 + c;
            float bia = bias_kv[128 + d];
            size_t base = (((size_t)bb * 128 + d) << 12) + nbase;
            #pragma unroll
            for (int rg = 0; rg < 4; ++rg) {
                floatx4 vv;
                #pragma unroll
                for (int r = 0; r < 4; ++r) vv[r] = acc[p][rg][r] + bia;
                store_bf4(v1T + base + rg * 16 + g * 4, vv);
            }
        }
    }
}

// ---------------------------------------------------------------- K2a: LN(islots) + qkv projection (per b,s)
__global__ __launch_bounds__(128)
void k2a_slots(const float* __restrict__ islots, const int* __restrict__ ip,
               const float* __restrict__ ln_s_g, const float* __restrict__ ln_s_b,
               const float* __restrict__ in_w, const float* __restrict__ in_b,
               const float* __restrict__ Wq_s, const float* __restrict__ bias_q,
               float* __restrict__ slbuf, float* __restrict__ qkvbuf,
               float* __restrict__ slotsA, float* __restrict__ qbuf) {
    __shared__ float sl[128];
    __shared__ float sn[128];
    __shared__ float red[4];
    int t = threadIdx.x;
    size_t bs = blockIdx.x;
    float x = islots[bs * 128 + t];
    float s1 = x, s2 = x * x;
    #pragma unroll
    for (int off = 32; off > 0; off >>= 1) { s1 += __shfl_xor(s1, off); s2 += __shfl_xor(s2, off); }
    if ((t & 63) == 0) { red[(t >> 6) * 2] = s1; red[(t >> 6) * 2 + 1] = s2; }
    __syncthreads();
    float tot1 = red[0] + red[2], tot2 = red[1] + red[3];
    float mean = tot1 * (1.f / 128.f), var = tot2 * (1.f / 128.f) - mean * mean;
    float rs = rsqrtf(var + 1e-5f);
    float slv = (x - mean) * rs * ln_s_g[t] + ln_s_b[t];
    sl[t] = slv;
    slbuf[bs * 128 + t] = slv;
    __syncthreads();
    int ival = *ip;
    if (ival != 1) {
        #pragma unroll
        for (int kI = 0; kI < 3; ++kI) {
            int e = t + kI * 128;
            qkvbuf[bs * 384 + e] = dot128(in_w + (size_t)e * 128, sl) + in_b[e];
        }
    } else {
        slotsA[bs * 128 + t] = slv;
        float q1 = slv, q2 = slv * slv;
        #pragma unroll
        for (int off = 32; off > 0; off >>= 1) { q1 += __shfl_xor(q1, off); q2 += __shfl_xor(q2, off); }
        __syncthreads();
        if ((t & 63) == 0) { red[(t >> 6) * 2] = q1; red[(t >> 6) * 2 + 1] = q2; }
        __syncthreads();
        float qt1 = red[0] + red[2], qt2 = red[1] + red[3];
        float qmean = qt1 * (1.f / 128.f), qvar = qt2 * (1.f / 128.f) - qmean * qmean;
        float qrs = rsqrtf(qvar + 1e-5f);
        sn[t] = (slv - qmean) * qrs;
        __syncthreads();
        qbuf[bs * 128 + t] = dot128(Wq_s + (size_t)t * 128, sn) + bias_q[t];
    }
}

// ---------------------------------------------------------------- K2b: MHA + MLP + q (per b,s)
__global__ __launch_bounds__(128)
void k2b_mha(const int* __restrict__ ip, const float* __restrict__ qkvbuf,
             const float* __restrict__ slbuf,
             const float* __restrict__ out_w, const float* __restrict__ out_b,
             const float* __restrict__ w1, const float* __restrict__ b1,
             const float* __restrict__ w2, const float* __restrict__ b2,
             const float* __restrict__ ln_s_g, const float* __restrict__ ln_s_b,
             const float* __restrict__ Wq_s, const float* __restrict__ bias_q,
             float* __restrict__ slotsA, float* __restrict__ qbuf) {
    if (*ip == 1) return;
    __shared__ float qv[128];
    __shared__ float att[4][12];
    __shared__ float oh[128];
    __shared__ float s3[128];
    __shared__ float h1[256];
    __shared__ float sn[128];
    __shared__ float red[4];
    int t = threadIdx.x;
    int bb = blockIdx.x / 11, s = blockIdx.x % 11;
    size_t base = (size_t)bb * 11;
    qv[t] = qkvbuf[(base + s) * 384 + t];
    __syncthreads();
    if (t < 44) {
        int h = t / 11, j = t % 11;
        const float* kr = qkvbuf + (base + j) * 384 + 128 + h * 32;
        const float* qr = &qv[h * 32];
        float a = 0.f;
        #pragma unroll
        for (int d = 0; d < 32; ++d) a += qr[d] * kr[d];
        att[h][j] = a * 0.17677669529663687f;
    }
    __syncthreads();
    if (t < 4) {
        float mx = -1e30f;
        #pragma unroll
        for (int j = 0; j < 11; ++j) mx = fmaxf(mx, att[t][j]);
        float sum = 0.f, e_[11];
        #pragma unroll
        for (int j = 0; j < 11; ++j) { e_[j] = __expf(att[t][j] - mx); sum += e_[j]; }
        float inv = 1.f / sum;
        #pragma unroll
        for (int j = 0; j < 11; ++j) att[t][j] = e_[j] * inv;
    }
    __syncthreads();
    {
        int h = t >> 5;
        float a = 0.f;
        #pragma unroll
        for (int j = 0; j < 11; ++j) a += att[h][j] * qkvbuf[(base + j) * 384 + 256 + t];
        oh[t] = a;
    }
    __syncthreads();
    float slv = slbuf[(base + s) * 128 + t];
    float s2v = slv + dot128(out_w + (size_t)t * 128, oh) + out_b[t];
    float s1 = s2v, s2 = s2v * s2v;
    #pragma unroll
    for (int off = 32; off > 0; off >>= 1) { s1 += __shfl_xor(s1, off); s2 += __shfl_xor(s2, off); }
    if ((t & 63) == 0) { red[(t >> 6) * 2] = s1; red[(t >> 6) * 2 + 1] = s2; }
    __syncthreads();
    float tot1 = red[0] + red[2], tot2 = red[1] + red[3];
    float mean = tot1 * (1.f / 128.f), var = tot2 * (1.f / 128.f) - mean * mean;
    float rs = rsqrtf(var + 1e-5f);
    float s3v = (s2v - mean) * rs * ln_s_g[t] + ln_s_b[t];
    s3[t] = s3v;
    __syncthreads();
    #pragma unroll
    for (int kI = 0; kI < 2; ++kI) {
        int k = t + kI * 128;
        float a = dot128(w1 + (size_t)k * 128, s3) + b1[k];
        h1[k] = a > 0.f ? a : 0.f;
    }
    __syncthreads();
    float fin = s3v + dot256(w2 + (size_t)t * 256, h1) + b2[t];
    slotsA[(base + s) * 128 + t] = fin;
    float q1 = fin, q2 = fin * fin;
    #pragma unroll
    for (int off = 32; off > 0; off >>= 1) { q1 += __shfl_xor(q1, off); q2 += __shfl_xor(q2, off); }
    __syncthreads();
    if ((t & 63) == 0) { red[(t >> 6) * 2] = q1; red[(t >> 6) * 2 + 1] = q2; }
    __syncthreads();
    float qt1 = red[0] + red[2], qt2 = red[1] + red[3];
    float qmean = qt1 * (1.f / 128.f), qvar = qt2 * (1.f / 128.f) - qmean * qmean;
    float qrs = rsqrtf(qvar + 1e-5f);
    sn[t] = (fin - qmean) * qrs;
    __syncthreads();
    qbuf[(base + s) * 128 + t] = dot128(Wq_s + (size_t)t * 128, sn) + bias_q[t];
}

// ---------------------------------------------------------------- K4: slot attention main (barrier-free, per-wave partials)
#define LGP 13
#define PPAD 72
struct K4Arena {
    float Lg[64][LGP];            // 3328 B
    unsigned short Pl[16][PPAD];  // 2304 B
};
__global__ __launch_bounds__(256)
void k4_attn(const unsigned short* __restrict__ k1, const unsigned short* __restrict__ v1T,
             const float* __restrict__ qbuf, float* __restrict__ Upart, float* __restrict__ Spart) {
    __shared__ K4Arena ar[4];   // 22528 B
    int t = threadIdx.x, lane = t & 63, wid = t >> 6;
    int bb = blockIdx.x >> 4;
    int part = blockIdx.x & 15;
    int n0 = part * 256 + wid * 64;
    int pidx = part * 4 + wid;   // 64 partials per batch
    int c = lane & 15, g = lane >> 4;
    K4Arena& A = ar[wid];

    short8 bq[4];
    #pragma unroll
    for (int kk = 0; kk < 4; ++kk) {
        short8 f;
        if (c < 11) {
            const floatx4* qp = (const floatx4*)(qbuf + ((size_t)bb * 11 + c) * 128 + kk * 32 + g * 8);
            floatx4 q0 = qp[0], q1 = qp[1];
            #pragma unroll
            for (int e = 0; e < 4; ++e) { f[e] = (short)f2bf(q0[e]); f[4 + e] = (short)f2bf(q1[e]); }
        } else {
            #pragma unroll
            for (int e = 0; e < 8; ++e) f[e] = 0;
        }
        bq[kk] = f;
    }

    floatx4 lac[4];
    #pragma unroll
    for (int t4 = 0; t4 < 4; ++t4) {
        lac[t4] = fzero4();
        #pragma unroll
        for (int kk = 0; kk < 4; ++kk) {
            const short8* ap = (const short8*)(k1 + ((size_t)bb * 4096 + n0 + t4 * 16 + c) * 128 + kk * 32 + g * 8);
            lac[t4] = __builtin_amdgcn_mfma_f32_16x16x32_bf16(*ap, bq[kk], lac[t4], 0, 0, 0);
        }
    }
    if (c < LGP) {
        #pragma unroll
        for (int t4 = 0; t4 < 4; ++t4)
            #pragma unroll
            for (int r = 0; r < 4; ++r)
                A.Lg[t4 * 16 + g * 4 + r][c] = lac[t4][r];
    }

    float p[11];
    {
        float mx = -1e30f;
        #pragma unroll
        for (int s = 0; s < 11; ++s) { p[s] = A.Lg[lane][s]; mx = fmaxf(mx, p[s]); }
        float sum = 0.f;
        #pragma unroll
        for (int s = 0; s < 11; ++s) { p[s] = __expf(p[s] - mx); sum += p[s]; }
        float inv = 1.f / sum;
        #pragma unroll
        for (int s = 0; s < 11; ++s) p[s] = p[s] * inv + 1e-8f;
    }
    #pragma unroll
    for (int s = 0; s < 11; ++s) A.Pl[s][lane] = f2bf(p[s]);

    floatx4 uac[8];
    floatx4 sac = fzero4();
    #pragma unroll
    for (int dt = 0; dt < 8; ++dt) uac[dt] = fzero4();
    short8 ones;
    #pragma unroll
    for (int e = 0; e < 8; ++e) ones[e] = (short)0x3F80;
    #pragma unroll
    for (int kk = 0; kk < 2; ++kk) {
        short8 ap = *(const short8*)(&A.Pl[c][kk * 32 + g * 8]);
        #pragma unroll
        for (int dt = 0; dt < 8; ++dt) {
            const short8* vp = (const short8*)(v1T + ((size_t)bb * 128 + dt * 16 + c) * 4096 + n0 + kk * 32 + g * 8);
            uac[dt] = __builtin_amdgcn_mfma_f32_16x16x32_bf16(ap, *vp, uac[dt], 0, 0, 0);
        }
        sac = __builtin_amdgcn_mfma_f32_16x16x32_bf16(ap, ones, sac, 0, 0, 0);
    }
    size_t ub = ((size_t)bb * 64 + pidx) * 11;
    #pragma unroll
    for (int r = 0; r < 4; ++r) {
        int s = g * 4 + r;
        if (s < 11) {
            #pragma unroll
            for (int dt = 0; dt < 8; ++dt)
                Upart[(ub + s) * 128 + dt * 16 + c] = uac[dt][r];
            if (c == 0) Spart[ub + s] = sac[r];
        }
    }
}

// ---------------------------------------------------------------- K5: reduce partials + GRU + LN + MLP (+ q)
__global__ __launch_bounds__(256)
void k5_gru(const float* __restrict__ Upart, const float* __restrict__ Spart,
            const float* __restrict__ slots_prev,
            const float* __restrict__ Wg,
            const float* __restrict__ bih, const float* __restrict__ bhh,
            const float* __restrict__ ln_m_g, const float* __restrict__ ln_m_b,
            const float* __restrict__ W1t, const float* __restrict__ b1,
            const float* __restrict__ W2t, const float* __restrict__ b2,
            const float* __restrict__ Wqt, const float* __restrict__ bias_q,
            float* __restrict__ out, float* __restrict__ qbuf, int compute_q) {
    __shared__ float updp[8][128];
    __shared__ float redS;
    __shared__ float upd[128];
    __shared__ float sp[128];
    __shared__ float gL[768];
    __shared__ float nsb[128];
    __shared__ float mrow[128];
    __shared__ float hrow[256];
    __shared__ float part2[2][128];
    __shared__ float red[4];
    __shared__ float snq[128];
    int t = threadIdx.x;
    int bb = blockIdx.x / 11, s = blockIdx.x % 11;
    size_t rowoff = ((size_t)bb * 11 + s) * 128;

    {
        int p = t >> 5, c4 = t & 31;
        size_t base = ((size_t)bb * 704 + s) * 128;
        floatx4 acc = fzero4();
        #pragma unroll
        for (int i = 0; i < 8; ++i) {
            const floatx4* rp = (const floatx4*)(Upart + base + (size_t)(p * 8 + i) * 1408);
            acc += rp[c4];
        }
        *(floatx4*)&updp[p][c4 * 4] = acc;
    }
    if (t < 64) {
        float sa = Spart[(size_t)bb * 704 + (size_t)t * 11 + s];
        #pragma unroll
        for (int off = 32; off > 0; off >>= 1) sa += __shfl_xor(sa, off);
        if (t == 0) redS = sa;
    }
    if (t < 128) sp[t] = slots_prev[rowoff + t];
    __syncthreads();
    if (t < 128) {
        float ua = 0.f;
        #pragma unroll
        for (int p = 0; p < 8; ++p) ua += updp[p][t];
        upd[t] = ua / redS;
    }
    __syncthreads();

    {
        const float* x1 = (t < 128) ? upd : sp;
        float a0 = 0.f, a1 = 0.f, a2 = 0.f;
        for (int j = 0; j < 128; ++j) {
            const float* wr = Wg + (size_t)j * 768;
            float xu = upd[j], xs = sp[j];
            a0 = fmaf(wr[t],       xu,    a0);
            a1 = fmaf(wr[t + 256], x1[j], a1);
            a2 = fmaf(wr[t + 512], xs,    a2);
        }
        float b0 = bih[t];
        float b1g = (t < 128) ? bih[t + 256] : bhh[t - 128];
        float b2g = bhh[t + 128];
        gL[t]       = a0 + b0;
        gL[t + 256] = a1 + b1g;
        gL[t + 512] = a2 + b2g;
    }
    __syncthreads();
    if (t < 128) {
        float r = 1.f / (1.f + __expf(-(gL[t] + gL[384 + t])));
        float z = 1.f / (1.f + __expf(-(gL[128 + t] + gL[512 + t])));
        float nn = tanhf(gL[256 + t] + r * gL[640 + t]);
        float ns = (1.f - z) * nn + z * sp[t];
        nsb[t] = ns;
        float s1 = ns, s2 = ns * ns;
        #pragma unroll
        for (int off = 32; off > 0; off >>= 1) { s1 += __shfl_xor(s1, off); s2 += __shfl_xor(s2, off); }
        if ((t & 63) == 0) { red[(t >> 6) * 2] = s1; red[(t >> 6) * 2 + 1] = s2; }
    }
    __syncthreads();
    if (t < 128) {
        float tot1 = red[0] + red[2], tot2 = red[1] + red[3];
        float mean = tot1 * (1.f / 128.f), var = tot2 * (1.f / 128.f) - mean * mean;
        float rs = rsqrtf(var + 1e-5f);
        mrow[t] = (nsb[t] - mean) * rs * ln_m_g[t] + ln_m_b[t];
    }
    __syncthreads();
    {
        float a = 0.f;
        for (int j = 0; j < 128; ++j) a = fmaf(W1t[(size_t)j * 256 + t], mrow[j], a);
        a += b1[t];
        hrow[t] = a > 0.f ? a : 0.f;
    }
    __syncthreads();
    {
        int half = t >> 7, e = t & 127;
        float a = 0.f;
        for (int j = 0; j < 128; ++j)
            a = fmaf(W2t[(size_t)(half * 128 + j) * 128 + e], hrow[half * 128 + j], a);
        part2[half][e] = a;
    }
    __syncthreads();
    float val = 0.f;
    if (t < 128) {
        val = nsb[t] + part2[0][t] + part2[1][t] + b2[t];
        out[rowoff + t] = val;
    }
    if (!compute_q) return;
    __syncthreads();
    if (t < 128) {
        float q1 = val, q2 = val * val;
        #pragma unroll
        for (int off = 32; off > 0; off >>= 1) { q1 += __shfl_xor(q1, off); q2 += __shfl_xor(q2, off); }
        if ((t & 63) == 0) { red[(t >> 6) * 2] = q1; red[(t >> 6) * 2 + 1] = q2; }
    }
    __syncthreads();
    if (t < 128) {
        float qt1 = red[0] + red[2], qt2 = red[1] + red[3];
        float qmean = qt1 * (1.f / 128.f), qvar = qt2 * (1.f / 128.f) - qmean * qmean;
        float qrs = rsqrtf(qvar + 1e-5f);
        snq[t] = (val - qmean) * qrs;
    }
    __syncthreads();
    {
        int half = t >> 7, e = t & 127;
        float a = 0.f;
        for (int j = 0; j < 64; ++j)
            a = fmaf(Wqt[(size_t)(half * 64 + j) * 128 + e], snq[half * 64 + j], a);
        part2[half][e] = a;
    }
    __syncthreads();
    if (t < 128)
        qbuf[rowoff + t] = part2[0][t] + part2[1][t] + bias_q[t];
}

// ---------------------------------------------------------------- host
extern "C" void kernel_launch(void* const* d_in, const int* in_sizes, int n_in,
                              void* d_out, int out_size, void* d_ws, size_t ws_size,
                              hipStream_t stream) {
    const float* inputs   = (const float*)d_in[0];
    const float* islots   = (const float*)d_in[1];
    const int*   ip       = (const int*)d_in[2];
    const float* ln_in_g  = (const float*)d_in[3];
    const float* ln_in_b  = (const float*)d_in[4];
    const float* ln_s_g   = (const float*)d_in[5];
    const float* ln_s_b   = (const float*)d_in[6];
    const float* ln_m_g   = (const float*)d_in[7];
    const float* ln_m_b   = (const float*)d_in[8];
    const float* mha_in_w = (const float*)d_in[9];
    const float* mha_in_b = (const float*)d_in[10];
    const float* mha_out_w= (const float*)d_in[11];
    const float* mha_out_b= (const float*)d_in[12];
    const float* attn_w1  = (const float*)d_in[13];
    const float* attn_b1  = (const float*)d_in[14];
    const float* attn_w2  = (const float*)d_in[15];
    const float* attn_b2  = (const float*)d_in[16];
    const float* Wq       = (const float*)d_in[17];
    const float* Wk       = (const float*)d_in[18];
    const float* Wv       = (const float*)d_in[19];
    const float* gru_wih  = (const float*)d_in[20];
    const float* gru_whh  = (const float*)d_in[21];
    const float* gru_bih  = (const float*)d_in[22];
    const float* gru_bhh  = (const float*)d_in[23];
    const float* mlp_w1   = (const float*)d_in[24];
    const float* mlp_b1   = (const float*)d_in[25];
    const float* mlp_w2   = (const float*)d_in[26];
    const float* mlp_b2   = (const float*)d_in[27];
    float* out = (float*)d_out;

    char* ws = (char*)d_ws;
    size_t off = 0;
    auto alloc = [&](size_t bytes) -> void* {
        void* p = ws + off;
        off += (bytes + 255) & ~(size_t)255;
        return p;
    };
    unsigned short* Wf    = (unsigned short*)alloc((size_t)256 * 192 * 2);
    float* bias_kv        = (float*)alloc(256 * 4);
    float* Wq_s           = (float*)alloc(128 * 128 * 4);
    float* bias_q         = (float*)alloc(128 * 4);
    unsigned short* k1    = (unsigned short*)alloc((size_t)64 * 4096 * 128 * 2);
    unsigned short* v1T   = (unsigned short*)alloc((size_t)64 * 128 * 4096 * 2);
    float* slotsA         = (float*)alloc((size_t)64 * 11 * 128 * 4);
    float* slotsB         = (float*)alloc((size_t)64 * 11 * 128 * 4);
    float* qbuf           = (float*)alloc((size_t)64 * 11 * 128 * 4);
    float* Upart          = (float*)alloc((size_t)64 * 64 * 11 * 128 * 4);
    float* Spart          = (float*)alloc((size_t)64 * 64 * 11 * 4);
    float* slbuf          = (float*)alloc((size_t)64 * 11 * 128 * 4);
    float* qkvbuf         = (float*)alloc((size_t)64 * 11 * 384 * 4);
    float* Wg             = (float*)alloc((size_t)128 * 768 * 4);
    float* W1t            = (float*)alloc((size_t)128 * 256 * 4);
    float* W2t            = (float*)alloc((size_t)256 * 128 * 4);
    float* Wqt            = (float*)alloc((size_t)128 * 128 * 4);
    (void)ws_size; (void)in_sizes; (void)n_in; (void)out_size;

    k0_prep<<<1024, 128, 0, stream>>>(Wk, Wv, ln_in_g, ln_in_b, Wq, ln_s_g, ln_s_b,
                                      gru_wih, gru_whh, mlp_w1, mlp_w2,
                                      Wf, bias_kv, Wq_s, bias_q, Wg, W1t, W2t, Wqt);
    k1_lnproj<<<4096, 512, 0, stream>>>(inputs, Wf, bias_kv, k1, v1T);
    k2a_slots<<<704, 128, 0, stream>>>(islots, ip, ln_s_g, ln_s_b, mha_in_w, mha_in_b,
                                       Wq_s, bias_q, slbuf, qkvbuf, slotsA, qbuf);
    k2b_mha<<<704, 128, 0, stream>>>(ip, qkvbuf, slbuf, mha_out_w, mha_out_b,
                                     attn_w1, attn_b1, attn_w2, attn_b2,
                                     ln_s_g, ln_s_b, Wq_s, bias_q, slotsA, qbuf);
    const float* sprev = slotsA;
    for (int it = 0; it < 2; ++it) {
        k4_attn<<<1024, 256, 0, stream>>>(k1, v1T, qbuf, Upart, Spart);
        float* dst = (it == 1) ? out : slotsB;
        k5_gru<<<704, 256, 0, stream>>>(Upart, Spart, sprev, Wg, gru_bih, gru_bhh,
                                        ln_m_g, ln_m_b, W1t, mlp_b1, W2t, mlp_b2,
                                        Wqt, bias_q, dst, qbuf, (it == 0) ? 1 : 0);
        sprev = dst;
    }
}

// Round 18
// 281.597 us; speedup vs baseline: 1.0549x; 1.0064x over previous
//
#include <hip/hip_runtime.h>

typedef __attribute__((ext_vector_type(8))) short short8;
typedef __attribute__((ext_vector_type(4))) float floatx4;

#define B_  64
#define N_  4096
#define DIN 192
#define S_  11
#define E_  128

__device__ inline unsigned short f2bf(float f) {
    union { float f; unsigned u; } v; v.f = f;
    unsigned r = v.u + 0x7FFF + ((v.u >> 16) & 1);
    return (unsigned short)(r >> 16);
}
__device__ inline floatx4 fzero4() { floatx4 v; v[0]=v[1]=v[2]=v[3]=0.f; return v; }
__device__ inline void store_bf4(unsigned short* dst, floatx4 v) {
    union { unsigned short u[4]; unsigned long long q; } o;
    o.u[0] = f2bf(v[0]); o.u[1] = f2bf(v[1]); o.u[2] = f2bf(v[2]); o.u[3] = f2bf(v[3]);
    *(unsigned long long*)dst = o.q;
}
__device__ inline float dot128(const float* __restrict__ w, const float* __restrict__ x) {
    const floatx4* wv = (const floatx4*)w;
    const floatx4* xv = (const floatx4*)x;
    float a = 0.f;
    for (int j = 0; j < 32; ++j) {
        floatx4 w_ = wv[j], x_ = xv[j];
        a += w_[0]*x_[0] + w_[1]*x_[1] + w_[2]*x_[2] + w_[3]*x_[3];
    }
    return a;
}
__device__ inline float dot256(const float* __restrict__ w, const float* __restrict__ x) {
    const floatx4* wv = (const floatx4*)w;
    const floatx4* xv = (const floatx4*)x;
    float a = 0.f;
    for (int j = 0; j < 64; ++j) {
        floatx4 w_ = wv[j], x_ = xv[j];
        a += w_[0]*x_[0] + w_[1]*x_[1] + w_[2]*x_[2] + w_[3]*x_[3];
    }
    return a;
}

// ---------------------------------------------------------------- K0: weight prep (merged k0 + k0t)
__global__ __launch_bounds__(128)
void k0_prep(const float* __restrict__ Wk, const float* __restrict__ Wv,
             const float* __restrict__ ln_in_g, const float* __restrict__ ln_in_b,
             const float* __restrict__ Wq, const float* __restrict__ ln_s_g,
             const float* __restrict__ ln_s_b,
             const float* __restrict__ wih, const float* __restrict__ whh,
             const float* __restrict__ w1, const float* __restrict__ w2,
             unsigned short* __restrict__ Wf, float* __restrict__ bias_kv,
             float* __restrict__ Wq_s, float* __restrict__ bias_q,
             float* __restrict__ Wg, float* __restrict__ W1t,
             float* __restrict__ W2t, float* __restrict__ Wqt) {
    int o = blockIdx.x, t = threadIdx.x;
    const float sc = 0.08838834764831845f;  // 1/sqrt(128)
    if (o < 384) {
        if (t >= 64) return;
        if (o < 256) {
            const float* src = (o < 128) ? (Wk + (size_t)o * DIN) : (Wv + (size_t)(o - 128) * DIN);
            int nt = o >> 4, cc = o & 15;
            float bs = 0.f;
            for (int j = t; j < DIN; j += 64) {
                float w = src[j];
                int kk = j >> 5, gg = (j >> 3) & 3, jj = j & 7;
                Wf[(size_t)(((nt * 6 + kk) << 6) + gg * 16 + cc) * 8 + jj] = f2bf(w * ln_in_g[j]);
                bs += w * ln_in_b[j];
            }
            #pragma unroll
            for (int off = 32; off > 0; off >>= 1) bs += __shfl_down(bs, off);
            if (t == 0) bias_kv[o] = bs;
        } else {
            int e = o - 256;
            float bs = 0.f;
            for (int j = t; j < E_; j += 64) {
                float w = Wq[(size_t)e * E_ + j];
                Wq_s[(size_t)e * E_ + j] = w * ln_s_g[j] * sc;
                bs += w * ln_s_b[j];
            }
            #pragma unroll
            for (int off = 32; off > 0; off >>= 1) bs += __shfl_down(bs, off);
            if (t == 0) bias_q[e] = bs * sc;
        }
    } else {
        int blk = o - 384;
        if (blk < 128) {
            int j = blk;
            for (int oo = t; oo < 768; oo += 128)
                Wg[(size_t)j * 768 + oo] = (oo < 384) ? wih[(size_t)oo * 128 + j]
                                                      : whh[(size_t)(oo - 384) * 128 + j];
        } else if (blk < 256) {
            int j = blk - 128;
            for (int k = t; k < 256; k += 128)
                W1t[(size_t)j * 256 + k] = w1[(size_t)k * 128 + j];
        } else if (blk < 512) {
            int j = blk - 256;
            W2t[(size_t)j * 128 + t] = w2[(size_t)t * 256 + j];
        } else {
            int j = blk - 512;
            Wqt[(size_t)j * 128 + t] = Wq[(size_t)t * 128 + j] * ln_s_g[j] * sc;
        }
    }
}

// ---------------------------------------------------------------- K1: LN + K/V projection (M=64, all-wave staging, staged coalesced stores)
#define KSTP 17   // K stage row pitch in short8 units (136 shorts)
#define VSTP 9    // V stage row pitch in short8 units (72 shorts)
__global__ __launch_bounds__(512, 2)
void k1_lnproj(const float* __restrict__ inp, const unsigned short* __restrict__ Wf,
               const float* __restrict__ bias_kv,
               unsigned short* __restrict__ k1o, unsigned short* __restrict__ v1T) {
    __shared__ short8 stage[64 * KSTP + 128 * VSTP];   // 2240 u = 35840 B; Al aliases front
    short8* Al = stage;                                // 1536 u = 24 KB (dead before stage writes)
    unsigned short* stK = (unsigned short*)stage;              // [64][136]
    unsigned short* stV = (unsigned short*)(stage + 64 * KSTP);// [128][72]
    int t = threadIdx.x, lane = t & 63, wid = t >> 6;
    long rowbase = (long)blockIdx.x * 64;
    int bb = (int)(rowbase >> 12);
    int nbase = (int)(rowbase & 4095);
    int c = lane & 15, g = lane >> 4;
    int nt0 = wid * 2;

    short8 wf[2][6];
    #pragma unroll
    for (int p = 0; p < 2; ++p)
        #pragma unroll
        for (int kk = 0; kk < 6; ++kk)
            wf[p][kk] = *(const short8*)(Wf + (size_t)(((nt0 + p) * 6 + kk) * 64 + lane) * 8);

    // ---- all-wave staging: thread t -> row r = t>>3, chunk q = t&7 (24 floats = 3 fragments)
    {
        int r = t >> 3, q = t & 7;
        const float* rp = inp + (rowbase + r) * DIN + q * 24;
        floatx4 x[6];
        #pragma unroll
        for (int i = 0; i < 6; ++i) x[i] = *(const floatx4*)(rp + i * 4);
        float s1 = 0.f, s2 = 0.f;
        #pragma unroll
        for (int i = 0; i < 6; ++i)
            #pragma unroll
            for (int e = 0; e < 4; ++e) { s1 += x[i][e]; s2 += x[i][e] * x[i][e]; }
        s1 += __shfl_xor(s1, 1); s1 += __shfl_xor(s1, 2); s1 += __shfl_xor(s1, 4);
        s2 += __shfl_xor(s2, 1); s2 += __shfl_xor(s2, 2); s2 += __shfl_xor(s2, 4);
        float mean = s1 * (1.f / 192.f);
        float var  = s2 * (1.f / 192.f) - mean * mean;
        float rsd  = rsqrtf(var + 1e-5f);
        int rg = r >> 4, cc = r & 15;
        #pragma unroll
        for (int f = 0; f < 3; ++f) {
            int F = q * 3 + f;
            int kk = F >> 2, gg = F & 3;
            short8 w;
            #pragma unroll
            for (int e = 0; e < 4; ++e) {
                w[e]     = (short)f2bf((x[2 * f][e]     - mean) * rsd);
                w[4 + e] = (short)f2bf((x[2 * f + 1][e] - mean) * rsd);
            }
            Al[(rg * 6 + kk) * 64 + gg * 16 + cc] = w;
        }
    }
    __syncthreads();

    floatx4 acc[2][4];
    #pragma unroll
    for (int p = 0; p < 2; ++p)
        #pragma unroll
        for (int rg = 0; rg < 4; ++rg) acc[p][rg] = fzero4();

    if (wid < 4) {
        #pragma unroll
        for (int rg = 0; rg < 4; ++rg)
            #pragma unroll
            for (int kk = 0; kk < 6; ++kk) {
                short8 a = Al[(rg * 6 + kk) * 64 + lane];
                acc[0][rg] = __builtin_amdgcn_mfma_f32_16x16x32_bf16(wf[0][kk], a, acc[0][rg], 0, 0, 0);
                acc[1][rg] = __builtin_amdgcn_mfma_f32_16x16x32_bf16(wf[1][kk], a, acc[1][rg], 0, 0, 0);
            }
    } else {
        #pragma unroll
        for (int rg = 0; rg < 4; ++rg)
            #pragma unroll
            for (int kk = 0; kk < 6; ++kk) {
                short8 a = Al[(rg * 6 + kk) * 64 + lane];
                acc[0][rg] = __builtin_amdgcn_mfma_f32_16x16x32_bf16(a, wf[0][kk], acc[0][rg], 0, 0, 0);
                acc[1][rg] = __builtin_amdgcn_mfma_f32_16x16x32_bf16(a, wf[1][kk], acc[1][rg], 0, 0, 0);
            }
    }
    __syncthreads();   // Al reads done; stage may overwrite

    if (wid < 4) {
        // K tiles -> stage[64][136]: row n = rg*16+c, col e = nt*16+g*4
        #pragma unroll
        for (int p = 0; p < 2; ++p) {
            int nt = nt0 + p;
            floatx4 bia = *(const floatx4*)(bias_kv + nt * 16 + g * 4);
            #pragma unroll
            for (int rg = 0; rg < 4; ++rg) {
                floatx4 vv;
                #pragma unroll
                for (int r = 0; r < 4; ++r) vv[r] = acc[p][rg][r] + bia[r];
                store_bf4(stK + (rg * 16 + c) * 136 + nt * 16 + g * 4, vv);
            }
        }
    } else {
        // V tiles -> stage[128][72]: row d, col n_local = rg*16+g*4
        #pragma unroll
        for (int p = 0; p < 2; ++p) {
            int d = (nt0 + p - 8) * 16 + c;
            float bia = bias_kv[128 + d];
            #pragma unroll
            for (int rg = 0; rg < 4; ++rg) {
                floatx4 vv;
                #pragma unroll
                for (int r = 0; r < 4; ++r) vv[r] = acc[p][rg][r] + bia;
                store_bf4(stV + d * 72 + rg * 16 + g * 4, vv);
            }
        }
    }
    __syncthreads();

    // ---- coalesced stream-out
    {
        short8* dstK = (short8*)(k1o + (size_t)rowbase * 128);
        const short8* sK = (const short8*)stK;
        const short8* sV = (const short8*)stV;
        #pragma unroll
        for (int m = 0; m < 2; ++m) {
            int idx = m * 512 + t;
            // K: 64 rows x 16 units (contiguous 16 KB)
            {
                int rw = idx >> 4, unit = idx & 15;
                dstK[idx] = sK[rw * KSTP + unit];
            }
            // V: 128 rows x 8 units, row stride 4096 shorts
            {
                int rw = idx >> 3, unit = idx & 7;
                *(short8*)(v1T + (((size_t)(bb * 128 + rw)) << 12) + nbase + unit * 8) = sV[rw * VSTP + unit];
            }
        }
    }
}

// ---------------------------------------------------------------- K2a: LN(islots) + qkv projection (per b,s)
__global__ __launch_bounds__(128)
void k2a_slots(const float* __restrict__ islots, const int* __restrict__ ip,
               const float* __restrict__ ln_s_g, const float* __restrict__ ln_s_b,
               const float* __restrict__ in_w, const float* __restrict__ in_b,
               const float* __restrict__ Wq_s, const float* __restrict__ bias_q,
               float* __restrict__ slbuf, float* __restrict__ qkvbuf,
               float* __restrict__ slotsA, float* __restrict__ qbuf) {
    __shared__ float sl[128];
    __shared__ float sn[128];
    __shared__ float red[4];
    int t = threadIdx.x;
    size_t bs = blockIdx.x;
    float x = islots[bs * 128 + t];
    float s1 = x, s2 = x * x;
    #pragma unroll
    for (int off = 32; off > 0; off >>= 1) { s1 += __shfl_xor(s1, off); s2 += __shfl_xor(s2, off); }
    if ((t & 63) == 0) { red[(t >> 6) * 2] = s1; red[(t >> 6) * 2 + 1] = s2; }
    __syncthreads();
    float tot1 = red[0] + red[2], tot2 = red[1] + red[3];
    float mean = tot1 * (1.f / 128.f), var = tot2 * (1.f / 128.f) - mean * mean;
    float rs = rsqrtf(var + 1e-5f);
    float slv = (x - mean) * rs * ln_s_g[t] + ln_s_b[t];
    sl[t] = slv;
    slbuf[bs * 128 + t] = slv;
    __syncthreads();
    int ival = *ip;
    if (ival != 1) {
        #pragma unroll
        for (int kI = 0; kI < 3; ++kI) {
            int e = t + kI * 128;
            qkvbuf[bs * 384 + e] = dot128(in_w + (size_t)e * 128, sl) + in_b[e];
        }
    } else {
        slotsA[bs * 128 + t] = slv;
        float q1 = slv, q2 = slv * slv;
        #pragma unroll
        for (int off = 32; off > 0; off >>= 1) { q1 += __shfl_xor(q1, off); q2 += __shfl_xor(q2, off); }
        __syncthreads();
        if ((t & 63) == 0) { red[(t >> 6) * 2] = q1; red[(t >> 6) * 2 + 1] = q2; }
        __syncthreads();
        float qt1 = red[0] + red[2], qt2 = red[1] + red[3];
        float qmean = qt1 * (1.f / 128.f), qvar = qt2 * (1.f / 128.f) - qmean * qmean;
        float qrs = rsqrtf(qvar + 1e-5f);
        sn[t] = (slv - qmean) * qrs;
        __syncthreads();
        qbuf[bs * 128 + t] = dot128(Wq_s + (size_t)t * 128, sn) + bias_q[t];
    }
}

// ---------------------------------------------------------------- K2b: MHA + MLP + q (per b,s)
__global__ __launch_bounds__(128)
void k2b_mha(const int* __restrict__ ip, const float* __restrict__ qkvbuf,
             const float* __restrict__ slbuf,
             const float* __restrict__ out_w, const float* __restrict__ out_b,
             const float* __restrict__ w1, const float* __restrict__ b1,
             const float* __restrict__ w2, const float* __restrict__ b2,
             const float* __restrict__ ln_s_g, const float* __restrict__ ln_s_b,
             const float* __restrict__ Wq_s, const float* __restrict__ bias_q,
             float* __restrict__ slotsA, float* __restrict__ qbuf) {
    if (*ip == 1) return;
    __shared__ float qv[128];
    __shared__ float att[4][12];
    __shared__ float oh[128];
    __shared__ float s3[128];
    __shared__ float h1[256];
    __shared__ float sn[128];
    __shared__ float red[4];
    int t = threadIdx.x;
    int bb = blockIdx.x / 11, s = blockIdx.x % 11;
    size_t base = (size_t)bb * 11;
    qv[t] = qkvbuf[(base + s) * 384 + t];
    __syncthreads();
    if (t < 44) {
        int h = t / 11, j = t % 11;
        const float* kr = qkvbuf + (base + j) * 384 + 128 + h * 32;
        const float* qr = &qv[h * 32];
        float a = 0.f;
        #pragma unroll
        for (int d = 0; d < 32; ++d) a += qr[d] * kr[d];
        att[h][j] = a * 0.17677669529663687f;
    }
    __syncthreads();
    if (t < 4) {
        float mx = -1e30f;
        #pragma unroll
        for (int j = 0; j < 11; ++j) mx = fmaxf(mx, att[t][j]);
        float sum = 0.f, e_[11];
        #pragma unroll
        for (int j = 0; j < 11; ++j) { e_[j] = __expf(att[t][j] - mx); sum += e_[j]; }
        float inv = 1.f / sum;
        #pragma unroll
        for (int j = 0; j < 11; ++j) att[t][j] = e_[j] * inv;
    }
    __syncthreads();
    {
        int h = t >> 5;
        float a = 0.f;
        #pragma unroll
        for (int j = 0; j < 11; ++j) a += att[h][j] * qkvbuf[(base + j) * 384 + 256 + t];
        oh[t] = a;
    }
    __syncthreads();
    float slv = slbuf[(base + s) * 128 + t];
    float s2v = slv + dot128(out_w + (size_t)t * 128, oh) + out_b[t];
    float s1 = s2v, s2 = s2v * s2v;
    #pragma unroll
    for (int off = 32; off > 0; off >>= 1) { s1 += __shfl_xor(s1, off); s2 += __shfl_xor(s2, off); }
    if ((t & 63) == 0) { red[(t >> 6) * 2] = s1; red[(t >> 6) * 2 + 1] = s2; }
    __syncthreads();
    float tot1 = red[0] + red[2], tot2 = red[1] + red[3];
    float mean = tot1 * (1.f / 128.f), var = tot2 * (1.f / 128.f) - mean * mean;
    float rs = rsqrtf(var + 1e-5f);
    float s3v = (s2v - mean) * rs * ln_s_g[t] + ln_s_b[t];
    s3[t] = s3v;
    __syncthreads();
    #pragma unroll
    for (int kI = 0; kI < 2; ++kI) {
        int k = t + kI * 128;
        float a = dot128(w1 + (size_t)k * 128, s3) + b1[k];
        h1[k] = a > 0.f ? a : 0.f;
    }
    __syncthreads();
    float fin = s3v + dot256(w2 + (size_t)t * 256, h1) + b2[t];
    slotsA[(base + s) * 128 + t] = fin;
    float q1 = fin, q2 = fin * fin;
    #pragma unroll
    for (int off = 32; off > 0; off >>= 1) { q1 += __shfl_xor(q1, off); q2 += __shfl_xor(q2, off); }
    __syncthreads();
    if ((t & 63) == 0) { red[(t >> 6) * 2] = q1; red[(t >> 6) * 2 + 1] = q2; }
    __syncthreads();
    float qt1 = red[0] + red[2], qt2 = red[1] + red[3];
    float qmean = qt1 * (1.f / 128.f), qvar = qt2 * (1.f / 128.f) - qmean * qmean;
    float qrs = rsqrtf(qvar + 1e-5f);
    sn[t] = (fin - qmean) * qrs;
    __syncthreads();
    qbuf[(base + s) * 128 + t] = dot128(Wq_s + (size_t)t * 128, sn) + bias_q[t];
}

// ---------------------------------------------------------------- K4: slot attention main (barrier-free, per-wave partials)
#define LGP 13
#define PPAD 72
struct K4Arena {
    float Lg[64][LGP];            // 3328 B
    unsigned short Pl[16][PPAD];  // 2304 B
};
__global__ __launch_bounds__(256)
void k4_attn(const unsigned short* __restrict__ k1, const unsigned short* __restrict__ v1T,
             const float* __restrict__ qbuf, float* __restrict__ Upart, float* __restrict__ Spart) {
    __shared__ K4Arena ar[4];   // 22528 B
    int t = threadIdx.x, lane = t & 63, wid = t >> 6;
    int bb = blockIdx.x >> 4;
    int part = blockIdx.x & 15;
    int n0 = part * 256 + wid * 64;
    int pidx = part * 4 + wid;   // 64 partials per batch
    int c = lane & 15, g = lane >> 4;
    K4Arena& A = ar[wid];

    short8 bq[4];
    #pragma unroll
    for (int kk = 0; kk < 4; ++kk) {
        short8 f;
        if (c < 11) {
            const floatx4* qp = (const floatx4*)(qbuf + ((size_t)bb * 11 + c) * 128 + kk * 32 + g * 8);
            floatx4 q0 = qp[0], q1 = qp[1];
            #pragma unroll
            for (int e = 0; e < 4; ++e) { f[e] = (short)f2bf(q0[e]); f[4 + e] = (short)f2bf(q1[e]); }
        } else {
            #pragma unroll
            for (int e = 0; e < 8; ++e) f[e] = 0;
        }
        bq[kk] = f;
    }

    floatx4 lac[4];
    #pragma unroll
    for (int t4 = 0; t4 < 4; ++t4) {
        lac[t4] = fzero4();
        #pragma unroll
        for (int kk = 0; kk < 4; ++kk) {
            const short8* ap = (const short8*)(k1 + ((size_t)bb * 4096 + n0 + t4 * 16 + c) * 128 + kk * 32 + g * 8);
            lac[t4] = __builtin_amdgcn_mfma_f32_16x16x32_bf16(*ap, bq[kk], lac[t4], 0, 0, 0);
        }
    }
    if (c < LGP) {
        #pragma unroll
        for (int t4 = 0; t4 < 4; ++t4)
            #pragma unroll
            for (int r = 0; r < 4; ++r)
                A.Lg[t4 * 16 + g * 4 + r][c] = lac[t4][r];
    }

    float p[11];
    {
        float mx = -1e30f;
        #pragma unroll
        for (int s = 0; s < 11; ++s) { p[s] = A.Lg[lane][s]; mx = fmaxf(mx, p[s]); }
        float sum = 0.f;
        #pragma unroll
        for (int s = 0; s < 11; ++s) { p[s] = __expf(p[s] - mx); sum += p[s]; }
        float inv = 1.f / sum;
        #pragma unroll
        for (int s = 0; s < 11; ++s) p[s] = p[s] * inv + 1e-8f;
    }
    #pragma unroll
    for (int s = 0; s < 11; ++s) A.Pl[s][lane] = f2bf(p[s]);

    floatx4 uac[8];
    floatx4 sac = fzero4();
    #pragma unroll
    for (int dt = 0; dt < 8; ++dt) uac[dt] = fzero4();
    short8 ones;
    #pragma unroll
    for (int e = 0; e < 8; ++e) ones[e] = (short)0x3F80;
    #pragma unroll
    for (int kk = 0; kk < 2; ++kk) {
        short8 ap = *(const short8*)(&A.Pl[c][kk * 32 + g * 8]);
        #pragma unroll
        for (int dt = 0; dt < 8; ++dt) {
            const short8* vp = (const short8*)(v1T + ((size_t)bb * 128 + dt * 16 + c) * 4096 + n0 + kk * 32 + g * 8);
            uac[dt] = __builtin_amdgcn_mfma_f32_16x16x32_bf16(ap, *vp, uac[dt], 0, 0, 0);
        }
        sac = __builtin_amdgcn_mfma_f32_16x16x32_bf16(ap, ones, sac, 0, 0, 0);
    }
    size_t ub = ((size_t)bb * 64 + pidx) * 11;
    #pragma unroll
    for (int r = 0; r < 4; ++r) {
        int s = g * 4 + r;
        if (s < 11) {
            #pragma unroll
            for (int dt = 0; dt < 8; ++dt)
                Upart[(ub + s) * 128 + dt * 16 + c] = uac[dt][r];
            if (c == 0) Spart[ub + s] = sac[r];
        }
    }
}

// ---------------------------------------------------------------- K5: reduce partials + GRU + LN + MLP (+ q)
__global__ __launch_bounds__(256)
void k5_gru(const float* __restrict__ Upart, const float* __restrict__ Spart,
            const float* __restrict__ slots_prev,
            const float* __restrict__ Wg,
            const float* __restrict__ bih, const float* __restrict__ bhh,
            const float* __restrict__ ln_m_g, const float* __restrict__ ln_m_b,
            const float* __restrict__ W1t, const float* __restrict__ b1,
            const float* __restrict__ W2t, const float* __restrict__ b2,
            const float* __restrict__ Wqt, const float* __restrict__ bias_q,
            float* __restrict__ out, float* __restrict__ qbuf, int compute_q) {
    __shared__ float updp[8][128];
    __shared__ float redS;
    __shared__ float upd[128];
    __shared__ float sp[128];
    __shared__ float gL[768];
    __shared__ float nsb[128];
    __shared__ float mrow[128];
    __shared__ float hrow[256];
    __shared__ float part2[2][128];
    __shared__ float red[4];
    __shared__ float snq[128];
    int t = threadIdx.x;
    int bb = blockIdx.x / 11, s = blockIdx.x % 11;
    size_t rowoff = ((size_t)bb * 11 + s) * 128;

    {
        int p = t >> 5, c4 = t & 31;
        size_t base = ((size_t)bb * 704 + s) * 128;
        floatx4 acc = fzero4();
        #pragma unroll
        for (int i = 0; i < 8; ++i) {
            const floatx4* rp = (const floatx4*)(Upart + base + (size_t)(p * 8 + i) * 1408);
            acc += rp[c4];
        }
        *(floatx4*)&updp[p][c4 * 4] = acc;
    }
    if (t < 64) {
        float sa = Spart[(size_t)bb * 704 + (size_t)t * 11 + s];
        #pragma unroll
        for (int off = 32; off > 0; off >>= 1) sa += __shfl_xor(sa, off);
        if (t == 0) redS = sa;
    }
    if (t < 128) sp[t] = slots_prev[rowoff + t];
    __syncthreads();
    if (t < 128) {
        float ua = 0.f;
        #pragma unroll
        for (int p = 0; p < 8; ++p) ua += updp[p][t];
        upd[t] = ua / redS;
    }
    __syncthreads();

    {
        const float* x1 = (t < 128) ? upd : sp;
        float a0 = 0.f, a1 = 0.f, a2 = 0.f;
        for (int j = 0; j < 128; ++j) {
            const float* wr = Wg + (size_t)j * 768;
            float xu = upd[j], xs = sp[j];
            a0 = fmaf(wr[t],       xu,    a0);
            a1 = fmaf(wr[t + 256], x1[j], a1);
            a2 = fmaf(wr[t + 512], xs,    a2);
        }
        float b0 = bih[t];
        float b1g = (t < 128) ? bih[t + 256] : bhh[t - 128];
        float b2g = bhh[t + 128];
        gL[t]       = a0 + b0;
        gL[t + 256] = a1 + b1g;
        gL[t + 512] = a2 + b2g;
    }
    __syncthreads();
    if (t < 128) {
        float r = 1.f / (1.f + __expf(-(gL[t] + gL[384 + t])));
        float z = 1.f / (1.f + __expf(-(gL[128 + t] + gL[512 + t])));
        float nn = tanhf(gL[256 + t] + r * gL[640 + t]);
        float ns = (1.f - z) * nn + z * sp[t];
        nsb[t] = ns;
        float s1 = ns, s2 = ns * ns;
        #pragma unroll
        for (int off = 32; off > 0; off >>= 1) { s1 += __shfl_xor(s1, off); s2 += __shfl_xor(s2, off); }
        if ((t & 63) == 0) { red[(t >> 6) * 2] = s1; red[(t >> 6) * 2 + 1] = s2; }
    }
    __syncthreads();
    if (t < 128) {
        float tot1 = red[0] + red[2], tot2 = red[1] + red[3];
        float mean = tot1 * (1.f / 128.f), var = tot2 * (1.f / 128.f) - mean * mean;
        float rs = rsqrtf(var + 1e-5f);
        mrow[t] = (nsb[t] - mean) * rs * ln_m_g[t] + ln_m_b[t];
    }
    __syncthreads();
    {
        float a = 0.f;
        for (int j = 0; j < 128; ++j) a = fmaf(W1t[(size_t)j * 256 + t], mrow[j], a);
        a += b1[t];
        hrow[t] = a > 0.f ? a : 0.f;
    }
    __syncthreads();
    {
        int half = t >> 7, e = t & 127;
        float a = 0.f;
        for (int j = 0; j < 128; ++j)
            a = fmaf(W2t[(size_t)(half * 128 + j) * 128 + e], hrow[half * 128 + j], a);
        part2[half][e] = a;
    }
    __syncthreads();
    float val = 0.f;
    if (t < 128) {
        val = nsb[t] + part2[0][t] + part2[1][t] + b2[t];
        out[rowoff + t] = val;
    }
    if (!compute_q) return;
    __syncthreads();
    if (t < 128) {
        float q1 = val, q2 = val * val;
        #pragma unroll
        for (int off = 32; off > 0; off >>= 1) { q1 += __shfl_xor(q1, off); q2 += __shfl_xor(q2, off); }
        if ((t & 63) == 0) { red[(t >> 6) * 2] = q1; red[(t >> 6) * 2 + 1] = q2; }
    }
    __syncthreads();
    if (t < 128) {
        float qt1 = red[0] + red[2], qt2 = red[1] + red[3];
        float qmean = qt1 * (1.f / 128.f), qvar = qt2 * (1.f / 128.f) - qmean * qmean;
        float qrs = rsqrtf(qvar + 1e-5f);
        snq[t] = (val - qmean) * qrs;
    }
    __syncthreads();
    {
        int half = t >> 7, e = t & 127;
        float a = 0.f;
        for (int j = 0; j < 64; ++j)
            a = fmaf(Wqt[(size_t)(half * 64 + j) * 128 + e], snq[half * 64 + j], a);
        part2[half][e] = a;
    }
    __syncthreads();
    if (t < 128)
        qbuf[rowoff + t] = part2[0][t] + part2[1][t] + bias_q[t];
}

// ---------------------------------------------------------------- host
extern "C" void kernel_launch(void* const* d_in, const int* in_sizes, int n_in,
                              void* d_out, int out_size, void* d_ws, size_t ws_size,
                              hipStream_t stream) {
    const float* inputs   = (const float*)d_in[0];
    const float* islots   = (const float*)d_in[1];
    const int*   ip       = (const int*)d_in[2];
    const float* ln_in_g  = (const float*)d_in[3];
    const float* ln_in_b  = (const float*)d_in[4];
    const float* ln_s_g   = (const float*)d_in[5];
    const float* ln_s_b   = (const float*)d_in[6];
    const float* ln_m_g   = (const float*)d_in[7];
    const float* ln_m_b   = (const float*)d_in[8];
    const float* mha_in_w = (const float*)d_in[9];
    const float* mha_in_b = (const float*)d_in[10];
    const float* mha_out_w= (const float*)d_in[11];
    const float* mha_out_b= (const float*)d_in[12];
    const float* attn_w1  = (const float*)d_in[13];
    const float* attn_b1  = (const float*)d_in[14];
    const float* attn_w2  = (const float*)d_in[15];
    const float* attn_b2  = (const float*)d_in[16];
    const float* Wq       = (const float*)d_in[17];
    const float* Wk       = (const float*)d_in[18];
    const float* Wv       = (const float*)d_in[19];
    const float* gru_wih  = (const float*)d_in[20];
    const float* gru_whh  = (const float*)d_in[21];
    const float* gru_bih  = (const float*)d_in[22];
    const float* gru_bhh  = (const float*)d_in[23];
    const float* mlp_w1   = (const float*)d_in[24];
    const float* mlp_b1   = (const float*)d_in[25];
    const float* mlp_w2   = (const float*)d_in[26];
    const float* mlp_b2   = (const float*)d_in[27];
    float* out = (float*)d_out;

    char* ws = (char*)d_ws;
    size_t off = 0;
    auto alloc = [&](size_t bytes) -> void* {
        void* p = ws + off;
        off += (bytes + 255) & ~(size_t)255;
        return p;
    };
    unsigned short* Wf    = (unsigned short*)alloc((size_t)256 * 192 * 2);
    float* bias_kv        = (float*)alloc(256 * 4);
    float* Wq_s           = (float*)alloc(128 * 128 * 4);
    float* bias_q         = (float*)alloc(128 * 4);
    unsigned short* k1    = (unsigned short*)alloc((size_t)64 * 4096 * 128 * 2);
    unsigned short* v1T   = (unsigned short*)alloc((size_t)64 * 128 * 4096 * 2);
    float* slotsA         = (float*)alloc((size_t)64 * 11 * 128 * 4);
    float* slotsB         = (float*)alloc((size_t)64 * 11 * 128 * 4);
    float* qbuf           = (float*)alloc((size_t)64 * 11 * 128 * 4);
    float* Upart          = (float*)alloc((size_t)64 * 64 * 11 * 128 * 4);
    float* Spart          = (float*)alloc((size_t)64 * 64 * 11 * 4);
    float* slbuf          = (float*)alloc((size_t)64 * 11 * 128 * 4);
    float* qkvbuf         = (float*)alloc((size_t)64 * 11 * 384 * 4);
    float* Wg             = (float*)alloc((size_t)128 * 768 * 4);
    float* W1t            = (float*)alloc((size_t)128 * 256 * 4);
    float* W2t            = (float*)alloc((size_t)256 * 128 * 4);
    float* Wqt            = (float*)alloc((size_t)128 * 128 * 4);
    (void)ws_size; (void)in_sizes; (void)n_in; (void)out_size;

    k0_prep<<<1024, 128, 0, stream>>>(Wk, Wv, ln_in_g, ln_in_b, Wq, ln_s_g, ln_s_b,
                                      gru_wih, gru_whh, mlp_w1, mlp_w2,
                                      Wf, bias_kv, Wq_s, bias_q, Wg, W1t, W2t, Wqt);
    k1_lnproj<<<4096, 512, 0, stream>>>(inputs, Wf, bias_kv, k1, v1T);
    k2a_slots<<<704, 128, 0, stream>>>(islots, ip, ln_s_g, ln_s_b, mha_in_w, mha_in_b,
                                       Wq_s, bias_q, slbuf, qkvbuf, slotsA, qbuf);
    k2b_mha<<<704, 128, 0, stream>>>(ip, qkvbuf, slbuf, mha_out_w, mha_out_b,
                                     attn_w1, attn_b1, attn_w2, attn_b2,
                                     ln_s_g, ln_s_b, Wq_s, bias_q, slotsA, qbuf);
    const float* sprev = slotsA;
    for (int it = 0; it < 2; ++it) {
        k4_attn<<<1024, 256, 0, stream>>>(k1, v1T, qbuf, Upart, Spart);
        float* dst = (it == 1) ? out : slotsB;
        k5_gru<<<704, 256, 0, stream>>>(Upart, Spart, sprev, Wg, gru_bih, gru_bhh,
                                        ln_m_g, ln_m_b, W1t, mlp_b1, W2t, mlp_b2,
                                        Wqt, bias_q, dst, qbuf, (it == 0) ? 1 : 0);
        sprev = dst;
    }
}